// Round 13
// baseline (504.181 us; speedup 1.0000x reference)
//
#include <hip/hip_runtime.h>
#include <hip/hip_bf16.h>

// Dense transformer forward, round 27: attn occupancy 2 -> 3 blocks/CU.
// R26 verdict: register-P PV (permlane + mfma32) regressed (502.7 vs 489.5);
// three different inner loops all sit at ~40us -> chain-latency-bound at
// 4 waves/SIMD. This round attacks the wave count: in the R24/R25 kernel,
// Q needs only 16 elems/row (DH=16) and is dead after the prologue, so the
// Q region (stride 16, rows 0..63) aliases the P region (stride 32 + XOR
// group swizzle, rows 0..31 — unchanged, loop-critical) in ONE [8][1024]
// buffer. LDS 64.25 -> 48.25KB -> 3 blocks/CU = 6 waves/SIMD (+50%).
// VGPR ~56 (R18 measured for this family) -> no VGPR cap. Loop body is
// byte-identical to R25; only prologue-only Q addresses changed. Numerics
// identical. oproj_ffn/gemm_fk/prep/head unchanged (R16/R18).
// B=64 x L=512, D=128, H=8 (DH=16), LAYERS=6, FF=512, OUT=10.

#define NROWS (64 * 512)
#define NLAYER 6

typedef __bf16 bf16x8 __attribute__((ext_vector_type(8)));
typedef float  f32x4  __attribute__((ext_vector_type(4)));
typedef float  f32x16 __attribute__((ext_vector_type(16)));

#define QSCALE 0.36067376022224085f   // 1/sqrt(16) * log2(e)

#if defined(__has_builtin)
#  if __has_builtin(__builtin_amdgcn_exp2f)
#    define FAST_EXP2(x) __builtin_amdgcn_exp2f(x)
#  endif
#endif
#ifndef FAST_EXP2
#  define FAST_EXP2(x) __expf((x) * 0.6931471805599453f)
#endif

__device__ __forceinline__ __hip_bfloat16 f2bf(float x) { return __float2bfloat16(x); }

__device__ __forceinline__ __hip_bfloat16 bf_rta(float a) {
  union { float f; unsigned u; } c{a};
  return __builtin_bit_cast(__hip_bfloat16, (unsigned short)((c.u + 0x8000u) >> 16));
}
__device__ __forceinline__ unsigned pk_rta(float a, float b) {
  union { float f; unsigned u; } ca{a}, cb{b};
  return ((ca.u + 0x8000u) >> 16) | ((cb.u + 0x8000u) & 0xFFFF0000u);
}
__device__ __forceinline__ float bf_hi(unsigned u) {          // element 1 of pair
  return __builtin_bit_cast(float, u & 0xFFFF0000u);
}
__device__ __forceinline__ float bf_lo(unsigned u) {          // element 0 of pair
  return __builtin_bit_cast(float, u << 16);
}

// ---------------------------------------------------------------------------
// Merged prep: x conversion + weight conversions/transposes + scaled qkv bias.
// ---------------------------------------------------------------------------
#define PN_X   (NROWS * 128)
#define PN_WP  (128 * 128)
#define PN_QW  (6 * 384 * 128)
#define PN_QB  (6 * 384)
#define PN_OW  (6 * 128 * 128)
#define PN_W1  (6 * 128 * 512)
#define PN_W2  (6 * 512 * 128)
#define PB1 PN_X
#define PB2 (PB1 + PN_WP)
#define PB3 (PB2 + PN_QW)
#define PB4 (PB3 + PN_QB)
#define PB5 (PB4 + PN_OW)
#define PB6 (PB5 + PN_W1)
#define PB7 (PB6 + PN_W2)

__global__ __launch_bounds__(256) void prep_kernel(
    const float* __restrict__ x, __hip_bfloat16* __restrict__ xb,
    const float* __restrict__ Wp, __hip_bfloat16* __restrict__ wp_t,
    const float* __restrict__ qkv_w, __hip_bfloat16* __restrict__ qkvw,
    const float* __restrict__ qkv_b, float* __restrict__ qb_s,
    const float* __restrict__ out_w, __hip_bfloat16* __restrict__ outw,
    const float* __restrict__ ffn_w1, __hip_bfloat16* __restrict__ w1t,
    const float* __restrict__ ffn_w2, __hip_bfloat16* __restrict__ w2t)
{
  const int idx = blockIdx.x * 256 + threadIdx.x;
  if (idx < PB1) {
    xb[idx] = f2bf(x[idx]);
  } else if (idx < PB2) {
    const int i = idx - PB1;
    const int c = i >> 7, r = i & 127;
    wp_t[i] = f2bf(Wp[r * 128 + c]);
  } else if (idx < PB3) {
    const int i = idx - PB2;
    const int row = (i >> 7) % 384;
    qkvw[i] = f2bf(qkv_w[i] * ((row < 128) ? QSCALE : 1.f));
  } else if (idx < PB4) {
    const int i = idx - PB3;
    qb_s[i] = qkv_b[i] * (((i % 384) < 128) ? QSCALE : 1.f);
  } else if (idx < PB5) {
    const int i = idx - PB4;
    outw[i] = f2bf(out_w[i]);
  } else if (idx < PB6) {
    const int i = idx - PB5;                 // [l][c][r], R=128, C=512
    const int l = i >> 16, j = i & 65535;
    const int c = j >> 7, r = j & 127;
    w1t[i] = f2bf(ffn_w1[l * 65536 + r * 512 + c]);
  } else if (idx < PB7) {
    const int i = idx - PB6;                 // [l][c][r], R=512, C=128
    const int l = i >> 16, j = i & 65535;
    const int c = j >> 9, r = j & 511;
    w2t[i] = f2bf(ffn_w2[l * 65536 + r * 128 + c]);
  }
}

// ---------------------------------------------------------------------------
// gemm_fk (unchanged, only used for the input projection).
// ---------------------------------------------------------------------------
__global__ __launch_bounds__(256) void gemm_fk(
    const __hip_bfloat16* __restrict__ A, const __hip_bfloat16* __restrict__ B,
    const float* __restrict__ bias, __hip_bfloat16* __restrict__ outb,
    __hip_bfloat16* __restrict__ hb,
    const float* __restrict__ lng, const float* __restrict__ lnb,
    int M, int K, int flags)
{
  __shared__ __align__(16) __hip_bfloat16 As[64 * 136];
  __shared__ __align__(16) __hip_bfloat16 Bs[128 * 136];

  const int tid = threadIdx.x;
  const int m0 = blockIdx.x << 6;
  const int wave = tid >> 6;
  const int lane = tid & 63;
  const int quad = lane >> 4;
  const int l15 = lane & 15;
  const int wrow = wave * 16;

  f32x4 acc[8];
#pragma unroll
  for (int ni = 0; ni < 8; ++ni) acc[ni] = (f32x4){0.f, 0.f, 0.f, 0.f};

  for (int kc = 0; kc < K; kc += 128) {
#pragma unroll
    for (int p = 0; p < 4; ++p) {
      const int e = tid + (p << 8);
      const int row = e >> 4;
      const int c = e & 15;
      *(uint4*)&As[row * 136 + c * 8] =
          *(const uint4*)(A + (size_t)(m0 + row) * K + kc + c * 8);
    }
#pragma unroll
    for (int p = 0; p < 8; ++p) {
      const int e = tid + (p << 8);
      const int row = e >> 4;
      const int c = e & 15;
      *(uint4*)&Bs[row * 136 + c * 8] =
          *(const uint4*)(B + (size_t)row * K + kc + c * 8);
    }
    __syncthreads();

#pragma unroll
    for (int ks = 0; ks < 4; ++ks) {
      const bf16x8 af = *(const bf16x8*)&As[(wrow + l15) * 136 + ks * 32 + quad * 8];
#pragma unroll
      for (int ni = 0; ni < 8; ++ni) {
        const bf16x8 bfr =
            *(const bf16x8*)&Bs[(ni * 16 + l15) * 136 + ks * 32 + quad * 8];
        acc[ni] = __builtin_amdgcn_mfma_f32_16x16x32_bf16(af, bfr, acc[ni], 0, 0, 0);
      }
    }
    if (kc + 128 < K) __syncthreads();
  }

  if (flags & 2) {
#pragma unroll
    for (int r = 0; r < 4; ++r) {
      const size_t row = (size_t)(m0 + wrow + quad * 4 + r);
      float s = 0.f, sq = 0.f;
#pragma unroll
      for (int ni = 0; ni < 8; ++ni) {
        const int cl = ni * 16 + l15;
        const float v = acc[ni][r] + bias[cl] +
                        __bfloat162float(hb[row * 128 + cl]);
        acc[ni][r] = v;
        s += v;
        sq += v * v;
      }
#pragma unroll
      for (int off = 1; off <= 8; off <<= 1) {
        s += __shfl_xor(s, off, 64);
        sq += __shfl_xor(sq, off, 64);
      }
      const float mean = s * (1.f / 128.f);
      const float var = sq * (1.f / 128.f) - mean * mean;
      const float rs = rsqrtf(var + 1e-5f);
#pragma unroll
      for (int ni = 0; ni < 8; ++ni) {
        const int cl = ni * 16 + l15;
        const float o = (acc[ni][r] - mean) * rs * lng[cl] + lnb[cl];
        hb[row * 128 + cl] = bf_rta(o);
      }
    }
  } else {
#pragma unroll
    for (int ni = 0; ni < 8; ++ni) {
      const int cl = ni * 16 + l15;
      const float bv = bias[cl];
#pragma unroll
      for (int r = 0; r < 4; ++r) {
        float v = acc[ni][r] + bv;
        if (flags & 1) v = fmaxf(v, 0.f);
        outb[(size_t)(m0 + wrow + quad * 4 + r) * 128 + cl] = bf_rta(v);
      }
    }
  }
}

// ---------------------------------------------------------------------------
// Fused outproj + residual + LN1 + FFN + residual + LN2 (R16 version).
// ---------------------------------------------------------------------------
__global__ __launch_bounds__(256) void oproj_ffn(
    const __hip_bfloat16* __restrict__ ab,   // attn output (A of outproj)
    __hip_bfloat16* __restrict__ hb,         // residual in, final out
    const __hip_bfloat16* __restrict__ ow,   // layer [128 n][128 k] bf16
    const float* __restrict__ ob,
    const float* __restrict__ ln1g, const float* __restrict__ ln1b,
    const __hip_bfloat16* __restrict__ w1,   // layer [512 n][128 k] bf16
    const __hip_bfloat16* __restrict__ w2,   // layer [128 n][512 k] bf16
    const float* __restrict__ fb1, const float* __restrict__ fb2,
    const float* __restrict__ ln2g, const float* __restrict__ ln2b)
{
  __shared__ __align__(16) __hip_bfloat16 AF[64 * 136];   // A / h1 / F
  __shared__ __align__(16) __hip_bfloat16 Bs[128 * 136];  // ow / W1c / W2c

  const int tid = threadIdx.x;
  const int m0 = blockIdx.x << 6;
  const int wave = tid >> 6;
  const int lane = tid & 63;
  const int quad = lane >> 4;
  const int l15 = lane & 15;
  const int wrow = wave * 16;
  const int node = m0 + wrow + l15;        // this lane's node (transposed lyt)
  const int ch0 = quad * 4;                // channel base within each ni group

  // ---- early residual load: 8x uint2; latency hides under staging+GEMM ----
  uint2 hres[8];
#pragma unroll
  for (int ni = 0; ni < 8; ++ni)
    hres[ni] = *(const uint2*)(hb + (size_t)node * 128 + ni * 16 + ch0);

  // ---- stage attnb tile (64x128) and ow (128x128) ----
#pragma unroll
  for (int p = 0; p < 4; ++p) {
    const int e = tid + (p << 8);
    const int row = e >> 4, c = e & 15;
    *(uint4*)&AF[row * 136 + c * 8] =
        *(const uint4*)(ab + (size_t)(m0 + row) * 128 + c * 8);
  }
#pragma unroll
  for (int p = 0; p < 8; ++p) {
    const int e = tid + (p << 8);
    const int row = e >> 4, c = e & 15;
    *(uint4*)&Bs[row * 136 + c * 8] =
        *(const uint4*)(ow + (size_t)row * 128 + c * 8);
  }
  __syncthreads();

  // attnb frags (node rows; usable as B-operand = A^T)
  bf16x8 af[4];
#pragma unroll
  for (int ks = 0; ks < 4; ++ks)
    af[ks] = *(const bf16x8*)&AF[(wrow + l15) * 136 + ks * 32 + quad * 8];

  // ---- outproj, transposed: acc[ni][r] = O[ch = ni*16+ch0+r][node] ----
  f32x4 acc[8];
#pragma unroll
  for (int ni = 0; ni < 8; ++ni) acc[ni] = (f32x4){0.f, 0.f, 0.f, 0.f};
#pragma unroll
  for (int ks = 0; ks < 4; ++ks)
#pragma unroll
    for (int ni = 0; ni < 8; ++ni) {
      const bf16x8 bfr =
          *(const bf16x8*)&Bs[(ni * 16 + l15) * 136 + ks * 32 + quad * 8];
      acc[ni] = __builtin_amdgcn_mfma_f32_16x16x32_bf16(bfr, af[ks], acc[ni], 0, 0, 0);
    }

  // ---- residual + LN1 (cross-quad reduce); h1 -> AF wave-private rows ----
  {
    float s = 0.f, sq = 0.f;
#pragma unroll
    for (int ni = 0; ni < 8; ++ni) {
      const f32x4 obv = *(const f32x4*)(ob + ni * 16 + ch0);
#pragma unroll
      for (int r = 0; r < 4; ++r) {
        const unsigned hu = (r & 2) ? hres[ni].y : hres[ni].x;
        const float hv = (r & 1) ? bf_hi(hu) : bf_lo(hu);
        const float v = acc[ni][r] + obv[r] + hv;
        acc[ni][r] = v;
        s += v;
        sq += v * v;
      }
    }
    s += __shfl_xor(s, 16, 64);  sq += __shfl_xor(sq, 16, 64);
    s += __shfl_xor(s, 32, 64);  sq += __shfl_xor(sq, 32, 64);
    const float mean = s * (1.f / 128.f);
    const float rs = rsqrtf(sq * (1.f / 128.f) - mean * mean + 1e-5f);
#pragma unroll
    for (int ni = 0; ni < 8; ++ni) {
      const f32x4 gv = *(const f32x4*)(ln1g + ni * 16 + ch0);
      const f32x4 bv = *(const f32x4*)(ln1b + ni * 16 + ch0);
      const float o0 = (acc[ni][0] - mean) * rs * gv[0] + bv[0];
      const float o1 = (acc[ni][1] - mean) * rs * gv[1] + bv[1];
      const float o2 = (acc[ni][2] - mean) * rs * gv[2] + bv[2];
      const float o3 = (acc[ni][3] - mean) * rs * gv[3] + bv[3];
      const uint2 pk = make_uint2(pk_rta(o0, o1), pk_rta(o2, o3));
      hres[ni] = pk;   // bf16 h1 for the LN2 residual (bit-exact vs AF copy)
      *(uint2*)&AF[(wrow + l15) * 136 + ni * 16 + ch0] = pk;
    }
  }

  // ---- FFN ----
  __syncthreads();   // all waves done reading ow from Bs
#pragma unroll
  for (int p = 0; p < 8; ++p) {     // stage W1 chunk 0
    const int e = tid + (p << 8);
    const int row = e >> 4, cc = e & 15;
    *(uint4*)&Bs[row * 136 + cc * 8] =
        *(const uint4*)(w1 + (size_t)row * 128 + cc * 8);
  }
  // h1 frags from AF (in-wave ordering vs this wave's LN writes)
  bf16x8 hf[4];
#pragma unroll
  for (int ks = 0; ks < 4; ++ks)
    hf[ks] = *(const bf16x8*)&AF[(wrow + l15) * 136 + ks * 32 + quad * 8];
  __syncthreads();   // W1c0 staged

  f32x4 facc[8];
#pragma unroll
  for (int ni = 0; ni < 8; ++ni) facc[ni] = (f32x4){0.f, 0.f, 0.f, 0.f};

  for (int c = 0; c < 4; ++c) {
    if (c > 0) {
      __syncthreads();   // W2 reads of previous chunk complete
#pragma unroll
      for (int p = 0; p < 8; ++p) {
        const int e = tid + (p << 8);
        const int row = e >> 4, cc = e & 15;
        *(uint4*)&Bs[row * 136 + cc * 8] =
            *(const uint4*)(w1 + (size_t)(c * 128 + row) * 128 + cc * 8);
      }
      __syncthreads();
    }

    // ---- F chunk, transposed: fc[ni] = F[n1 = ni*16+ch0+r][node] ----
    f32x4 fc[8];
#pragma unroll
    for (int ni = 0; ni < 8; ++ni) fc[ni] = (f32x4){0.f, 0.f, 0.f, 0.f};
#pragma unroll
    for (int ks = 0; ks < 4; ++ks)
#pragma unroll
      for (int ni = 0; ni < 8; ++ni) {
        const bf16x8 wf =
            *(const bf16x8*)&Bs[(ni * 16 + l15) * 136 + ks * 32 + quad * 8];
        fc[ni] = __builtin_amdgcn_mfma_f32_16x16x32_bf16(wf, hf[ks], fc[ni], 0, 0, 0);
      }
    // bias + relu + pack into AF[node row][n1 = ni*16 + ch0 + r]
#pragma unroll
    for (int ni = 0; ni < 8; ++ni) {
      const f32x4 bv = *(const f32x4*)(fb1 + c * 128 + ni * 16 + ch0);
      const float v0 = fmaxf(fc[ni][0] + bv[0], 0.f);
      const float v1 = fmaxf(fc[ni][1] + bv[1], 0.f);
      const float v2 = fmaxf(fc[ni][2] + bv[2], 0.f);
      const float v3 = fmaxf(fc[ni][3] + bv[3], 0.f);
      *(uint2*)&AF[(wrow + l15) * 136 + ni * 16 + ch0] =
          make_uint2(pk_rta(v0, v1), pk_rta(v2, v3));
    }
    __syncthreads();   // all waves done reading W1c from Bs

    // ---- stage W2 chunk c (k = c*128 .. +128 of [128][512]) ----
#pragma unroll
    for (int p = 0; p < 8; ++p) {
      const int e = tid + (p << 8);
      const int row = e >> 4, cc = e & 15;
      *(uint4*)&Bs[row * 136 + cc * 8] =
          *(const uint4*)(w2 + (size_t)row * 512 + c * 128 + cc * 8);
    }
    __syncthreads();

    // ---- out += W2_c @ F_c, transposed: facc[ni][r] = out[ch][node] ----
#pragma unroll
    for (int ks2 = 0; ks2 < 4; ++ks2) {
      const bf16x8 ff =
          *(const bf16x8*)&AF[(wrow + l15) * 136 + ks2 * 32 + quad * 8];
#pragma unroll
      for (int ni = 0; ni < 8; ++ni) {
        const bf16x8 wf =
            *(const bf16x8*)&Bs[(ni * 16 + l15) * 136 + ks2 * 32 + quad * 8];
        facc[ni] = __builtin_amdgcn_mfma_f32_16x16x32_bf16(wf, ff, facc[ni], 0, 0, 0);
      }
    }
  }

  // ---- final residual (hres regs) + LN2 -> hb, vectorized stores ----
  {
    float s = 0.f, sq = 0.f;
#pragma unroll
    for (int ni = 0; ni < 8; ++ni) {
      const f32x4 b2v = *(const f32x4*)(fb2 + ni * 16 + ch0);
#pragma unroll
      for (int r = 0; r < 4; ++r) {
        const unsigned hu = (r & 2) ? hres[ni].y : hres[ni].x;
        const float hv = (r & 1) ? bf_hi(hu) : bf_lo(hu);
        const float v = facc[ni][r] + b2v[r] + hv;
        facc[ni][r] = v;
        s += v;
        sq += v * v;
      }
    }
    s += __shfl_xor(s, 16, 64);  sq += __shfl_xor(sq, 16, 64);
    s += __shfl_xor(s, 32, 64);  sq += __shfl_xor(sq, 32, 64);
    const float mean = s * (1.f / 128.f);
    const float rs = rsqrtf(sq * (1.f / 128.f) - mean * mean + 1e-5f);
#pragma unroll
    for (int ni = 0; ni < 8; ++ni) {
      const f32x4 gv = *(const f32x4*)(ln2g + ni * 16 + ch0);
      const f32x4 bv = *(const f32x4*)(ln2b + ni * 16 + ch0);
      const float o0 = (facc[ni][0] - mean) * rs * gv[0] + bv[0];
      const float o1 = (facc[ni][1] - mean) * rs * gv[1] + bv[1];
      const float o2 = (facc[ni][2] - mean) * rs * gv[2] + bv[2];
      const float o3 = (facc[ni][3] - mean) * rs * gv[3] + bv[3];
      *(uint2*)(hb + (size_t)node * 128 + ni * 16 + ch0) =
          make_uint2(pk_rta(o0, o1), pk_rta(o2, o3));
    }
  }
}

// ---------------------------------------------------------------------------
// Fused QKV + flash attention (R27): R24/R25 8-wave kernel with PQ shrunk to
// [8][1024] — Q staged at stride 16 (rows 0..63, prologue-only, read to regs
// before any P write) aliasing P at stride 32 + XOR group swizzle (rows
// 0..31, loop path byte-identical to R25). Ks [512][16] XOR-swizzled; uint2
// prologue staging. LDS = 16384 + 16640 + 16384 = 48.25KB -> 3 blocks/CU
// (24 waves/CU, 6/SIMD — was 4/SIMD).
// ---------------------------------------------------------------------------
__global__ __launch_bounds__(512) void attn_kernel(
    const __hip_bfloat16* __restrict__ hbf,
    const __hip_bfloat16* __restrict__ qkvw_l,
    const float* __restrict__ qb_l,
    __hip_bfloat16* __restrict__ o)
{
  __shared__ __align__(16) __hip_bfloat16 Ks[512 * 16];
  __shared__ __align__(16) __hip_bfloat16 Vt[16 * 520];
  __shared__ __align__(16) __hip_bfloat16 PQ[8][1024];

  const int tid = threadIdx.x;
  const int b = blockIdx.x & 63;        // XCD-aware: graph in low bits
  const int hh = blockIdx.x >> 6;
  const __hip_bfloat16* hrow = hbf + (size_t)b * 512 * 128;

  const int wave = tid >> 6;            // 0..7
  const int lane = tid & 63;
  const int l31 = lane & 31;
  const int l5 = lane >> 5;
  const int l15 = lane & 15;
  const int quad = lane >> 4;
  const int q0 = wave * 64;             // this wave's query slice

  {
    // Q,K swapped (lane owns node=l15, dh=quad*4+r); V = mfma(hf,wv)
    // (lane owns dh=l15, nodes quad*4+r). All staging writes are uint2.
    f32x4 qacc[4], kacc[4], vacc[4];
#pragma unroll
    for (int mt = 0; mt < 4; ++mt) {
      qacc[mt] = (f32x4){0.f, 0.f, 0.f, 0.f};
      kacc[mt] = (f32x4){0.f, 0.f, 0.f, 0.f};
      vacc[mt] = (f32x4){0.f, 0.f, 0.f, 0.f};
    }
#pragma unroll
    for (int ks = 0; ks < 4; ++ks) {
      const int kc = ks * 32 + quad * 8;
      const bf16x8 wq = *(const bf16x8*)(qkvw_l + (size_t)(hh * 16 + l15) * 128 + kc);
      const bf16x8 wk = *(const bf16x8*)(qkvw_l + (size_t)(128 + hh * 16 + l15) * 128 + kc);
      const bf16x8 wv = *(const bf16x8*)(qkvw_l + (size_t)(256 + hh * 16 + l15) * 128 + kc);
#pragma unroll
      for (int mt = 0; mt < 4; ++mt) {
        const bf16x8 hf =
            *(const bf16x8*)(hrow + (size_t)(q0 + mt * 16 + l15) * 128 + kc);
        qacc[mt] = __builtin_amdgcn_mfma_f32_16x16x32_bf16(wq, hf, qacc[mt], 0, 0, 0);
        kacc[mt] = __builtin_amdgcn_mfma_f32_16x16x32_bf16(wk, hf, kacc[mt], 0, 0, 0);
        vacc[mt] = __builtin_amdgcn_mfma_f32_16x16x32_bf16(hf, wv, vacc[mt], 0, 0, 0);
      }
    }
    const f32x4 qbv = *(const f32x4*)(qb_l + hh * 16 + quad * 4);
    const f32x4 kbv = *(const f32x4*)(qb_l + 128 + hh * 16 + quad * 4);
    const float vbs = qb_l[256 + hh * 16 + l15];
#pragma unroll
    for (int mt = 0; mt < 4; ++mt) {
      // Q[row = mt*16+l15][dh = quad*4 .. +3] -> stride-16 Q region
      // (prologue-only; aliased with P, consumed into regs before P writes)
      *(uint2*)&PQ[wave][(mt * 16 + l15) * 16 + quad * 4] =
          make_uint2(pk_rta(qacc[mt][0] + qbv[0], qacc[mt][1] + qbv[1]),
                     pk_rta(qacc[mt][2] + qbv[2], qacc[mt][3] + qbv[3]));
      // K[row = q0+mt*16+l15][dh = quad*4 .. +3] -> Ks, swizzled
      {
        const int krow = q0 + mt * 16 + l15;
        const int ke = (krow * 16 + quad * 4) ^ ((l15 & 7) << 3);
        *(uint2*)&Ks[ke] =
            make_uint2(pk_rta(kacc[mt][0] + kbv[0], kacc[mt][1] + kbv[1]),
                       pk_rta(kacc[mt][2] + kbv[2], kacc[mt][3] + kbv[3]));
      }
      // V[dh = l15][nodes q0+mt*16+quad*4 .. +3] -> Vt
      *(uint2*)&Vt[l15 * 520 + q0 + mt * 16 + quad * 4] =
          make_uint2(pk_rta(vacc[mt][0] + vbs, vacc[mt][1] + vbs),
                     pk_rta(vacc[mt][2] + vbs, vacc[mt][3] + vbs));
    }
  }

  // qf into regs BEFORE any P write (in-wave alias ordering); stride 16.
  bf16x8 qf[2];
#pragma unroll
  for (int s = 0; s < 2; ++s)
    qf[s] = *(const bf16x8*)&PQ[wave][(s * 32 + l31) * 16 + l5 * 8];
  __syncthreads();

  __hip_bfloat16* Pw = &PQ[wave][0];
  const f32x16 z16 = {};
  f32x4 oacc[2][2];
#pragma unroll
  for (int s = 0; s < 2; ++s) { oacc[s][0] = (f32x4){0.f,0.f,0.f,0.f};
                                oacc[s][1] = (f32x4){0.f,0.f,0.f,0.f}; }
  float lacc[2] = {0.f, 0.f};

  const int psw = (l31 >> 1) & 3;       // P-write row swizzle (row = l31)
  const int prs = (l15 >> 1) & 3;       // P-read row swizzle (row = g*16+l15)

  // per-lane swizzled K base (elem): (l31*16 + l5*8) ^ ((l31&7)<<3)
  const int kbase = (l31 * 16 + l5 * 8) ^ ((l31 & 7) << 3);

  // ---- pipeline prologue: kf and st for step (kt=0, s=0) ----
  bf16x8 kf = *(const bf16x8*)&Ks[kbase];
  f32x16 st0 = __builtin_amdgcn_mfma_f32_32x32x16_bf16(kf, qf[0], z16, 0, 0, 0);

  for (int kt = 0; kt < 16; ++kt) {
    const bf16x8 vf = *(const bf16x8*)&Vt[l15 * 520 + kt * 32 + quad * 8];

    // ================= step (kt, s=0): uses st0 (computed a step ago) ====
    {
      float pr[16];
#pragma unroll
      for (int r = 0; r < 16; ++r) pr[r] = FAST_EXP2(st0[r]);
      const float a0 = (pr[0] + pr[1]) + (pr[2] + pr[3]);
      const float a1 = (pr[4] + pr[5]) + (pr[6] + pr[7]);
      const float a2 = (pr[8] + pr[9]) + (pr[10] + pr[11]);
      const float a3 = (pr[12] + pr[13]) + (pr[14] + pr[15]);
      lacc[0] += (a0 + a1) + (a2 + a3);
#pragma unroll
      for (int g = 0; g < 4; ++g) {
        *(uint2*)&Pw[l31 * 32 + ((g ^ psw)) * 8 + l5 * 4] =
            make_uint2(pk_rta(pr[g * 4 + 0], pr[g * 4 + 1]),
                       pk_rta(pr[g * 4 + 2], pr[g * 4 + 3]));
      }
    }
    // next step's QK^T (s=1, same kf) — hides P write->read turnaround
    f32x16 st1 = __builtin_amdgcn_mfma_f32_32x32x16_bf16(kf, qf[1], z16, 0, 0, 0);
#pragma unroll
    for (int g = 0; g < 2; ++g) {
      const bf16x8 pf =
          *(const bf16x8*)&Pw[(g * 16 + l15) * 32 + ((quad ^ prs)) * 8];
      oacc[0][g] = __builtin_amdgcn_mfma_f32_16x16x32_bf16(vf, pf, oacc[0][g], 0, 0, 0);
    }

    // ================= step (kt, s=1): uses st1 =========================
    {
      float pr[16];
#pragma unroll
      for (int r = 0; r < 16; ++r) pr[r] = FAST_EXP2(st1[r]);
      const float a0 = (pr[0] + pr[1]) + (pr[2] + pr[3]);
      const float a1 = (pr[4] + pr[5]) + (pr[6] + pr[7]);
      const float a2 = (pr[8] + pr[9]) + (pr[10] + pr[11]);
      const float a3 = (pr[12] + pr[13]) + (pr[14] + pr[15]);
      lacc[1] += (a0 + a1) + (a2 + a3);
#pragma unroll
      for (int g = 0; g < 4; ++g) {
        *(uint2*)&Pw[l31 * 32 + ((g ^ psw)) * 8 + l5 * 4] =
            make_uint2(pk_rta(pr[g * 4 + 0], pr[g * 4 + 1]),
                       pk_rta(pr[g * 4 + 2], pr[g * 4 + 3]));
      }
    }
    // next kt's kf load + QK^T (s=0) — hides P write->read turnaround
    if (kt < 15) {
      kf = *(const bf16x8*)&Ks[(kt + 1) * 512 + kbase];
      st0 = __builtin_amdgcn_mfma_f32_32x32x16_bf16(kf, qf[0], z16, 0, 0, 0);
    }
#pragma unroll
    for (int g = 0; g < 2; ++g) {
      const bf16x8 pf =
          *(const bf16x8*)&Pw[(g * 16 + l15) * 32 + ((quad ^ prs)) * 8];
      oacc[1][g] = __builtin_amdgcn_mfma_f32_16x16x32_bf16(vf, pf, oacc[1][g], 0, 0, 0);
    }
  }

#pragma unroll
  for (int s = 0; s < 2; ++s) {
    const float lv = lacc[s] + __shfl_xor(lacc[s], 32, 64);
#pragma unroll
    for (int g = 0; g < 2; ++g) {
      const float lq = __shfl(lv, g * 16 + l15, 64);
      const float inv = 1.f / lq;
      const int qrow = q0 + s * 32 + g * 16 + l15;
      *(uint2*)(o + ((size_t)b * 512 + qrow) * 128 + hh * 16 + quad * 4) =
          make_uint2(pk_rta(oacc[s][g][0] * inv, oacc[s][g][1] * inv),
                     pk_rta(oacc[s][g][2] * inv, oacc[s][g][3] * inv));
    }
  }
}

// ---------------------------------------------------------------------------
// Mean-pool (bf16 h) + 128->64 relu -> 64->10 head. One block per graph.
// ---------------------------------------------------------------------------
__global__ __launch_bounds__(256) void head_kernel(
    const __hip_bfloat16* __restrict__ h,
    const float* __restrict__ w1, const float* __restrict__ b1,
    const float* __restrict__ w2, const float* __restrict__ b2,
    float* __restrict__ out)
{
  __shared__ float part[2][128];
  __shared__ float pooled[128];
  __shared__ float hid[64];

  const int b = blockIdx.x;
  const int tid = threadIdx.x;
  const int d = tid & 127;
  const int half = tid >> 7;

  const __hip_bfloat16* hp = h + ((size_t)b * 512 + (size_t)half * 256) * 128;
  float s = 0.f;
  for (int r = 0; r < 256; ++r) s += __bfloat162float(hp[(size_t)r * 128 + d]);
  part[half][d] = s;
  __syncthreads();

  if (tid < 128) pooled[tid] = (part[0][tid] + part[1][tid]) * (1.f / 512.f);
  __syncthreads();

  if (tid < 64) {
    float a = b1[tid];
    for (int dd = 0; dd < 128; ++dd) a = fmaf(pooled[dd], w1[dd * 64 + tid], a);
    hid[tid] = fmaxf(a, 0.f);
  }
  __syncthreads();

  if (tid < 10) {
    float a = b2[tid];
    for (int j = 0; j < 64; ++j) a = fmaf(hid[j], w2[j * 10 + tid], a);
    out[b * 10 + tid] = a;
  }
}

// ---------------------------------------------------------------------------
extern "C" void kernel_launch(void* const* d_in, const int* in_sizes, int n_in,
                              void* d_out, int out_size, void* d_ws, size_t ws_size,
                              hipStream_t stream)
{
  (void)in_sizes; (void)n_in; (void)out_size; (void)ws_size;

  const float* x      = (const float*)d_in[0];
  const float* Wp     = (const float*)d_in[4];
  const float* bp     = (const float*)d_in[5];
  const float* qkv_w  = (const float*)d_in[6];
  const float* qkv_b  = (const float*)d_in[7];
  const float* out_w  = (const float*)d_in[8];
  const float* out_b  = (const float*)d_in[9];
  const float* ln1_g  = (const float*)d_in[10];
  const float* ln1_b  = (const float*)d_in[11];
  const float* ffn_w1 = (const float*)d_in[12];
  const float* ffn_b1 = (const float*)d_in[13];
  const float* ffn_w2 = (const float*)d_in[14];
  const float* ffn_b2 = (const float*)d_in[15];
  const float* ln2_g  = (const float*)d_in[16];
  const float* ln2_b  = (const float*)d_in[17];
  const float* cw1    = (const float*)d_in[18];
  const float* cb1    = (const float*)d_in[19];
  const float* cw2    = (const float*)d_in[20];
  const float* cb2    = (const float*)d_in[21];

  const int N = NROWS;

  // ws (bf16 activations): hbf | xb | attnb | weights | qb_s
  __hip_bfloat16* hbf   = (__hip_bfloat16*)d_ws;
  __hip_bfloat16* xb    = hbf + (size_t)N * 128;
  __hip_bfloat16* attnb = xb + (size_t)N * 128;
  __hip_bfloat16* wp_t  = attnb + (size_t)N * 128;
  __hip_bfloat16* qkvw  = wp_t + 128 * 128;
  __hip_bfloat16* outw  = qkvw + 6 * 384 * 128;
  __hip_bfloat16* w1t   = outw + 6 * 128 * 128;
  __hip_bfloat16* w2t   = w1t + 6 * 512 * 128;
  float* qb_s = (float*)(w2t + 6 * 128 * 512);

  const dim3 blk(256);
  __hip_bfloat16* const nob = (__hip_bfloat16*)nullptr;
  const float* const nof = (const float*)nullptr;

  // ---- single merged prep dispatch ----
  prep_kernel<<<dim3((PB7 + 255) / 256), blk, 0, stream>>>(
      x, xb, Wp, wp_t, qkv_w, qkvw, qkv_b, qb_s, out_w, outw,
      ffn_w1, w1t, ffn_w2, w2t);

  // ---- input projection: hbf = bf16(x @ Wp + bp) ----
  gemm_fk<<<dim3(N / 64), blk, 0, stream>>>(
      xb, wp_t, bp, hbf, nob, nof, nof, N, 128, 0);

  for (int i = 0; i < NLAYER; ++i) {
    // fused QKV + attention (XCD-swizzled grid, 8 waves/block, 3 blocks/CU)
    attn_kernel<<<dim3(64 * 8), dim3(512), 0, stream>>>(
        hbf, qkvw + (size_t)i * 384 * 128, qb_s + (size_t)i * 384, attnb);

    // hbf = LN2( h1 + relu(h1@W1+b1)@W2 + b2 ), h1 = LN1(hbf + attnb@ow^T + ob)
    oproj_ffn<<<dim3(N / 64), blk, 0, stream>>>(
        attnb, hbf,
        outw + (size_t)i * 128 * 128, out_b + (size_t)i * 128,
        ln1_g + (size_t)i * 128, ln1_b + (size_t)i * 128,
        w1t + (size_t)i * 512 * 128, w2t + (size_t)i * 128 * 512,
        ffn_b1 + (size_t)i * 512, ffn_b2 + (size_t)i * 128,
        ln2_g + (size_t)i * 128, ln2_b + (size_t)i * 128);
  }

  head_kernel<<<dim3(64), blk, 0, stream>>>(hbf, cw1, cb1, cw2, cb2, (float*)d_out);
}

// Round 14
// 483.366 us; speedup vs baseline: 1.0431x; 1.0431x over previous
//
#include <hip/hip_runtime.h>
#include <hip/hip_bf16.h>

// Dense transformer forward, round 28: FINAL — exact revert to R19, the
// session's best-measured kernel (484.3us). R20-R27 explored 8 attn
// variants (16-wave occupancy, Ks/P swizzles, stride changes, register-P
// via permlane, LDS trims): all landed at 40-46us attn vs R19's ~40 —
// the inner chain is serial-dependency/VALU-bound, not LDS- or
// occupancy-bound (grid 512 = hard 2 blocks/CU cap). Locking in the
// measured optimum. Structure: merged prep; gemm_fk inproj; 6x [fused
// QKV+flash-attn (8 waves, P stride 40, (kt,s) two-stage st prefetch) +
// oproj_ffn (transposed epilogues, fused residual+LN1+FFN+LN2)]; head.
// B=64 x L=512, D=128, H=8 (DH=16), LAYERS=6, FF=512, OUT=10.

#define NROWS (64 * 512)
#define NLAYER 6

typedef __bf16 bf16x8 __attribute__((ext_vector_type(8)));
typedef float  f32x4  __attribute__((ext_vector_type(4)));
typedef float  f32x16 __attribute__((ext_vector_type(16)));

#define QSCALE 0.36067376022224085f   // 1/sqrt(16) * log2(e)

#if defined(__has_builtin)
#  if __has_builtin(__builtin_amdgcn_exp2f)
#    define FAST_EXP2(x) __builtin_amdgcn_exp2f(x)
#  endif
#endif
#ifndef FAST_EXP2
#  define FAST_EXP2(x) __expf((x) * 0.6931471805599453f)
#endif

__device__ __forceinline__ __hip_bfloat16 f2bf(float x) { return __float2bfloat16(x); }

__device__ __forceinline__ __hip_bfloat16 bf_rta(float a) {
  union { float f; unsigned u; } c{a};
  return __builtin_bit_cast(__hip_bfloat16, (unsigned short)((c.u + 0x8000u) >> 16));
}
__device__ __forceinline__ unsigned pk_rta(float a, float b) {
  union { float f; unsigned u; } ca{a}, cb{b};
  return ((ca.u + 0x8000u) >> 16) | ((cb.u + 0x8000u) & 0xFFFF0000u);
}
__device__ __forceinline__ float bf_hi(unsigned u) {          // element 1 of pair
  return __builtin_bit_cast(float, u & 0xFFFF0000u);
}
__device__ __forceinline__ float bf_lo(unsigned u) {          // element 0 of pair
  return __builtin_bit_cast(float, u << 16);
}

// ---------------------------------------------------------------------------
// Merged prep: x conversion + weight conversions/transposes + scaled qkv bias.
// ---------------------------------------------------------------------------
#define PN_X   (NROWS * 128)
#define PN_WP  (128 * 128)
#define PN_QW  (6 * 384 * 128)
#define PN_QB  (6 * 384)
#define PN_OW  (6 * 128 * 128)
#define PN_W1  (6 * 128 * 512)
#define PN_W2  (6 * 512 * 128)
#define PB1 PN_X
#define PB2 (PB1 + PN_WP)
#define PB3 (PB2 + PN_QW)
#define PB4 (PB3 + PN_QB)
#define PB5 (PB4 + PN_OW)
#define PB6 (PB5 + PN_W1)
#define PB7 (PB6 + PN_W2)

__global__ __launch_bounds__(256) void prep_kernel(
    const float* __restrict__ x, __hip_bfloat16* __restrict__ xb,
    const float* __restrict__ Wp, __hip_bfloat16* __restrict__ wp_t,
    const float* __restrict__ qkv_w, __hip_bfloat16* __restrict__ qkvw,
    const float* __restrict__ qkv_b, float* __restrict__ qb_s,
    const float* __restrict__ out_w, __hip_bfloat16* __restrict__ outw,
    const float* __restrict__ ffn_w1, __hip_bfloat16* __restrict__ w1t,
    const float* __restrict__ ffn_w2, __hip_bfloat16* __restrict__ w2t)
{
  const int idx = blockIdx.x * 256 + threadIdx.x;
  if (idx < PB1) {
    xb[idx] = f2bf(x[idx]);
  } else if (idx < PB2) {
    const int i = idx - PB1;
    const int c = i >> 7, r = i & 127;
    wp_t[i] = f2bf(Wp[r * 128 + c]);
  } else if (idx < PB3) {
    const int i = idx - PB2;
    const int row = (i >> 7) % 384;
    qkvw[i] = f2bf(qkv_w[i] * ((row < 128) ? QSCALE : 1.f));
  } else if (idx < PB4) {
    const int i = idx - PB3;
    qb_s[i] = qkv_b[i] * (((i % 384) < 128) ? QSCALE : 1.f);
  } else if (idx < PB5) {
    const int i = idx - PB4;
    outw[i] = f2bf(out_w[i]);
  } else if (idx < PB6) {
    const int i = idx - PB5;                 // [l][c][r], R=128, C=512
    const int l = i >> 16, j = i & 65535;
    const int c = j >> 7, r = j & 127;
    w1t[i] = f2bf(ffn_w1[l * 65536 + r * 512 + c]);
  } else if (idx < PB7) {
    const int i = idx - PB6;                 // [l][c][r], R=512, C=128
    const int l = i >> 16, j = i & 65535;
    const int c = j >> 9, r = j & 511;
    w2t[i] = f2bf(ffn_w2[l * 65536 + r * 128 + c]);
  }
}

// ---------------------------------------------------------------------------
// gemm_fk (unchanged, only used for the input projection).
// ---------------------------------------------------------------------------
__global__ __launch_bounds__(256) void gemm_fk(
    const __hip_bfloat16* __restrict__ A, const __hip_bfloat16* __restrict__ B,
    const float* __restrict__ bias, __hip_bfloat16* __restrict__ outb,
    __hip_bfloat16* __restrict__ hb,
    const float* __restrict__ lng, const float* __restrict__ lnb,
    int M, int K, int flags)
{
  __shared__ __align__(16) __hip_bfloat16 As[64 * 136];
  __shared__ __align__(16) __hip_bfloat16 Bs[128 * 136];

  const int tid = threadIdx.x;
  const int m0 = blockIdx.x << 6;
  const int wave = tid >> 6;
  const int lane = tid & 63;
  const int quad = lane >> 4;
  const int l15 = lane & 15;
  const int wrow = wave * 16;

  f32x4 acc[8];
#pragma unroll
  for (int ni = 0; ni < 8; ++ni) acc[ni] = (f32x4){0.f, 0.f, 0.f, 0.f};

  for (int kc = 0; kc < K; kc += 128) {
#pragma unroll
    for (int p = 0; p < 4; ++p) {
      const int e = tid + (p << 8);
      const int row = e >> 4;
      const int c = e & 15;
      *(uint4*)&As[row * 136 + c * 8] =
          *(const uint4*)(A + (size_t)(m0 + row) * K + kc + c * 8);
    }
#pragma unroll
    for (int p = 0; p < 8; ++p) {
      const int e = tid + (p << 8);
      const int row = e >> 4;
      const int c = e & 15;
      *(uint4*)&Bs[row * 136 + c * 8] =
          *(const uint4*)(B + (size_t)row * K + kc + c * 8);
    }
    __syncthreads();

#pragma unroll
    for (int ks = 0; ks < 4; ++ks) {
      const bf16x8 af = *(const bf16x8*)&As[(wrow + l15) * 136 + ks * 32 + quad * 8];
#pragma unroll
      for (int ni = 0; ni < 8; ++ni) {
        const bf16x8 bfr =
            *(const bf16x8*)&Bs[(ni * 16 + l15) * 136 + ks * 32 + quad * 8];
        acc[ni] = __builtin_amdgcn_mfma_f32_16x16x32_bf16(af, bfr, acc[ni], 0, 0, 0);
      }
    }
    if (kc + 128 < K) __syncthreads();
  }

  if (flags & 2) {
#pragma unroll
    for (int r = 0; r < 4; ++r) {
      const size_t row = (size_t)(m0 + wrow + quad * 4 + r);
      float s = 0.f, sq = 0.f;
#pragma unroll
      for (int ni = 0; ni < 8; ++ni) {
        const int cl = ni * 16 + l15;
        const float v = acc[ni][r] + bias[cl] +
                        __bfloat162float(hb[row * 128 + cl]);
        acc[ni][r] = v;
        s += v;
        sq += v * v;
      }
#pragma unroll
      for (int off = 1; off <= 8; off <<= 1) {
        s += __shfl_xor(s, off, 64);
        sq += __shfl_xor(sq, off, 64);
      }
      const float mean = s * (1.f / 128.f);
      const float var = sq * (1.f / 128.f) - mean * mean;
      const float rs = rsqrtf(var + 1e-5f);
#pragma unroll
      for (int ni = 0; ni < 8; ++ni) {
        const int cl = ni * 16 + l15;
        const float o = (acc[ni][r] - mean) * rs * lng[cl] + lnb[cl];
        hb[row * 128 + cl] = bf_rta(o);
      }
    }
  } else {
#pragma unroll
    for (int ni = 0; ni < 8; ++ni) {
      const int cl = ni * 16 + l15;
      const float bv = bias[cl];
#pragma unroll
      for (int r = 0; r < 4; ++r) {
        float v = acc[ni][r] + bv;
        if (flags & 1) v = fmaxf(v, 0.f);
        outb[(size_t)(m0 + wrow + quad * 4 + r) * 128 + cl] = bf_rta(v);
      }
    }
  }
}

// ---------------------------------------------------------------------------
// Fused outproj + residual + LN1 + FFN + residual + LN2 (R16 version).
// ---------------------------------------------------------------------------
__global__ __launch_bounds__(256) void oproj_ffn(
    const __hip_bfloat16* __restrict__ ab,   // attn output (A of outproj)
    __hip_bfloat16* __restrict__ hb,         // residual in, final out
    const __hip_bfloat16* __restrict__ ow,   // layer [128 n][128 k] bf16
    const float* __restrict__ ob,
    const float* __restrict__ ln1g, const float* __restrict__ ln1b,
    const __hip_bfloat16* __restrict__ w1,   // layer [512 n][128 k] bf16
    const __hip_bfloat16* __restrict__ w2,   // layer [128 n][512 k] bf16
    const float* __restrict__ fb1, const float* __restrict__ fb2,
    const float* __restrict__ ln2g, const float* __restrict__ ln2b)
{
  __shared__ __align__(16) __hip_bfloat16 AF[64 * 136];   // A / h1 / F
  __shared__ __align__(16) __hip_bfloat16 Bs[128 * 136];  // ow / W1c / W2c

  const int tid = threadIdx.x;
  const int m0 = blockIdx.x << 6;
  const int wave = tid >> 6;
  const int lane = tid & 63;
  const int quad = lane >> 4;
  const int l15 = lane & 15;
  const int wrow = wave * 16;
  const int node = m0 + wrow + l15;        // this lane's node (transposed lyt)
  const int ch0 = quad * 4;                // channel base within each ni group

  // ---- early residual load: 8x uint2; latency hides under staging+GEMM ----
  uint2 hres[8];
#pragma unroll
  for (int ni = 0; ni < 8; ++ni)
    hres[ni] = *(const uint2*)(hb + (size_t)node * 128 + ni * 16 + ch0);

  // ---- stage attnb tile (64x128) and ow (128x128) ----
#pragma unroll
  for (int p = 0; p < 4; ++p) {
    const int e = tid + (p << 8);
    const int row = e >> 4, c = e & 15;
    *(uint4*)&AF[row * 136 + c * 8] =
        *(const uint4*)(ab + (size_t)(m0 + row) * 128 + c * 8);
  }
#pragma unroll
  for (int p = 0; p < 8; ++p) {
    const int e = tid + (p << 8);
    const int row = e >> 4, c = e & 15;
    *(uint4*)&Bs[row * 136 + c * 8] =
        *(const uint4*)(ow + (size_t)row * 128 + c * 8);
  }
  __syncthreads();

  // attnb frags (node rows; usable as B-operand = A^T)
  bf16x8 af[4];
#pragma unroll
  for (int ks = 0; ks < 4; ++ks)
    af[ks] = *(const bf16x8*)&AF[(wrow + l15) * 136 + ks * 32 + quad * 8];

  // ---- outproj, transposed: acc[ni][r] = O[ch = ni*16+ch0+r][node] ----
  f32x4 acc[8];
#pragma unroll
  for (int ni = 0; ni < 8; ++ni) acc[ni] = (f32x4){0.f, 0.f, 0.f, 0.f};
#pragma unroll
  for (int ks = 0; ks < 4; ++ks)
#pragma unroll
    for (int ni = 0; ni < 8; ++ni) {
      const bf16x8 bfr =
          *(const bf16x8*)&Bs[(ni * 16 + l15) * 136 + ks * 32 + quad * 8];
      acc[ni] = __builtin_amdgcn_mfma_f32_16x16x32_bf16(bfr, af[ks], acc[ni], 0, 0, 0);
    }

  // ---- residual + LN1 (cross-quad reduce); h1 -> AF wave-private rows ----
  {
    float s = 0.f, sq = 0.f;
#pragma unroll
    for (int ni = 0; ni < 8; ++ni) {
      const f32x4 obv = *(const f32x4*)(ob + ni * 16 + ch0);
#pragma unroll
      for (int r = 0; r < 4; ++r) {
        const unsigned hu = (r & 2) ? hres[ni].y : hres[ni].x;
        const float hv = (r & 1) ? bf_hi(hu) : bf_lo(hu);
        const float v = acc[ni][r] + obv[r] + hv;
        acc[ni][r] = v;
        s += v;
        sq += v * v;
      }
    }
    s += __shfl_xor(s, 16, 64);  sq += __shfl_xor(sq, 16, 64);
    s += __shfl_xor(s, 32, 64);  sq += __shfl_xor(sq, 32, 64);
    const float mean = s * (1.f / 128.f);
    const float rs = rsqrtf(sq * (1.f / 128.f) - mean * mean + 1e-5f);
#pragma unroll
    for (int ni = 0; ni < 8; ++ni) {
      const f32x4 gv = *(const f32x4*)(ln1g + ni * 16 + ch0);
      const f32x4 bv = *(const f32x4*)(ln1b + ni * 16 + ch0);
      const float o0 = (acc[ni][0] - mean) * rs * gv[0] + bv[0];
      const float o1 = (acc[ni][1] - mean) * rs * gv[1] + bv[1];
      const float o2 = (acc[ni][2] - mean) * rs * gv[2] + bv[2];
      const float o3 = (acc[ni][3] - mean) * rs * gv[3] + bv[3];
      const uint2 pk = make_uint2(pk_rta(o0, o1), pk_rta(o2, o3));
      hres[ni] = pk;   // bf16 h1 for the LN2 residual (bit-exact vs AF copy)
      *(uint2*)&AF[(wrow + l15) * 136 + ni * 16 + ch0] = pk;
    }
  }

  // ---- FFN ----
  __syncthreads();   // all waves done reading ow from Bs
#pragma unroll
  for (int p = 0; p < 8; ++p) {     // stage W1 chunk 0
    const int e = tid + (p << 8);
    const int row = e >> 4, cc = e & 15;
    *(uint4*)&Bs[row * 136 + cc * 8] =
        *(const uint4*)(w1 + (size_t)row * 128 + cc * 8);
  }
  // h1 frags from AF (in-wave ordering vs this wave's LN writes)
  bf16x8 hf[4];
#pragma unroll
  for (int ks = 0; ks < 4; ++ks)
    hf[ks] = *(const bf16x8*)&AF[(wrow + l15) * 136 + ks * 32 + quad * 8];
  __syncthreads();   // W1c0 staged

  f32x4 facc[8];
#pragma unroll
  for (int ni = 0; ni < 8; ++ni) facc[ni] = (f32x4){0.f, 0.f, 0.f, 0.f};

  for (int c = 0; c < 4; ++c) {
    if (c > 0) {
      __syncthreads();   // W2 reads of previous chunk complete
#pragma unroll
      for (int p = 0; p < 8; ++p) {
        const int e = tid + (p << 8);
        const int row = e >> 4, cc = e & 15;
        *(uint4*)&Bs[row * 136 + cc * 8] =
            *(const uint4*)(w1 + (size_t)(c * 128 + row) * 128 + cc * 8);
      }
      __syncthreads();
    }

    // ---- F chunk, transposed: fc[ni] = F[n1 = ni*16+ch0+r][node] ----
    f32x4 fc[8];
#pragma unroll
    for (int ni = 0; ni < 8; ++ni) fc[ni] = (f32x4){0.f, 0.f, 0.f, 0.f};
#pragma unroll
    for (int ks = 0; ks < 4; ++ks)
#pragma unroll
      for (int ni = 0; ni < 8; ++ni) {
        const bf16x8 wf =
            *(const bf16x8*)&Bs[(ni * 16 + l15) * 136 + ks * 32 + quad * 8];
        fc[ni] = __builtin_amdgcn_mfma_f32_16x16x32_bf16(wf, hf[ks], fc[ni], 0, 0, 0);
      }
    // bias + relu + pack into AF[node row][n1 = ni*16 + ch0 + r]
#pragma unroll
    for (int ni = 0; ni < 8; ++ni) {
      const f32x4 bv = *(const f32x4*)(fb1 + c * 128 + ni * 16 + ch0);
      const float v0 = fmaxf(fc[ni][0] + bv[0], 0.f);
      const float v1 = fmaxf(fc[ni][1] + bv[1], 0.f);
      const float v2 = fmaxf(fc[ni][2] + bv[2], 0.f);
      const float v3 = fmaxf(fc[ni][3] + bv[3], 0.f);
      *(uint2*)&AF[(wrow + l15) * 136 + ni * 16 + ch0] =
          make_uint2(pk_rta(v0, v1), pk_rta(v2, v3));
    }
    __syncthreads();   // all waves done reading W1c from Bs

    // ---- stage W2 chunk c (k = c*128 .. +128 of [128][512]) ----
#pragma unroll
    for (int p = 0; p < 8; ++p) {
      const int e = tid + (p << 8);
      const int row = e >> 4, cc = e & 15;
      *(uint4*)&Bs[row * 136 + cc * 8] =
          *(const uint4*)(w2 + (size_t)row * 512 + c * 128 + cc * 8);
    }
    __syncthreads();

    // ---- out += W2_c @ F_c, transposed: facc[ni][r] = out[ch][node] ----
#pragma unroll
    for (int ks2 = 0; ks2 < 4; ++ks2) {
      const bf16x8 ff =
          *(const bf16x8*)&AF[(wrow + l15) * 136 + ks2 * 32 + quad * 8];
#pragma unroll
      for (int ni = 0; ni < 8; ++ni) {
        const bf16x8 wf =
            *(const bf16x8*)&Bs[(ni * 16 + l15) * 136 + ks2 * 32 + quad * 8];
        facc[ni] = __builtin_amdgcn_mfma_f32_16x16x32_bf16(wf, ff, facc[ni], 0, 0, 0);
      }
    }
  }

  // ---- final residual (hres regs) + LN2 -> hb, vectorized stores ----
  {
    float s = 0.f, sq = 0.f;
#pragma unroll
    for (int ni = 0; ni < 8; ++ni) {
      const f32x4 b2v = *(const f32x4*)(fb2 + ni * 16 + ch0);
#pragma unroll
      for (int r = 0; r < 4; ++r) {
        const unsigned hu = (r & 2) ? hres[ni].y : hres[ni].x;
        const float hv = (r & 1) ? bf_hi(hu) : bf_lo(hu);
        const float v = facc[ni][r] + b2v[r] + hv;
        facc[ni][r] = v;
        s += v;
        sq += v * v;
      }
    }
    s += __shfl_xor(s, 16, 64);  sq += __shfl_xor(sq, 16, 64);
    s += __shfl_xor(s, 32, 64);  sq += __shfl_xor(sq, 32, 64);
    const float mean = s * (1.f / 128.f);
    const float rs = rsqrtf(sq * (1.f / 128.f) - mean * mean + 1e-5f);
#pragma unroll
    for (int ni = 0; ni < 8; ++ni) {
      const f32x4 gv = *(const f32x4*)(ln2g + ni * 16 + ch0);
      const f32x4 bv = *(const f32x4*)(ln2b + ni * 16 + ch0);
      const float o0 = (facc[ni][0] - mean) * rs * gv[0] + bv[0];
      const float o1 = (facc[ni][1] - mean) * rs * gv[1] + bv[1];
      const float o2 = (facc[ni][2] - mean) * rs * gv[2] + bv[2];
      const float o3 = (facc[ni][3] - mean) * rs * gv[3] + bv[3];
      *(uint2*)(hb + (size_t)node * 128 + ni * 16 + ch0) =
          make_uint2(pk_rta(o0, o1), pk_rta(o2, o3));
    }
  }
}

// ---------------------------------------------------------------------------
// Fused QKV + flash attention (R19): R16 config (P stride 40, single buffer,
// PQ[8][1536], no setprio) + two-stage (kt,s) software pipeline: st for the
// NEXT step is computed between the current step's P-write and P-read.
// Single-buffer WAR safety: same-wave DS ops are in-order; the next write is
// issued after the current reads in program order (R16 invariant).
// ---------------------------------------------------------------------------
__global__ __launch_bounds__(512) void attn_kernel(
    const __hip_bfloat16* __restrict__ hbf,
    const __hip_bfloat16* __restrict__ qkvw_l,
    const float* __restrict__ qb_l,
    __hip_bfloat16* __restrict__ o)
{
  __shared__ __align__(16) __hip_bfloat16 Ks[512 * 24];
  __shared__ __align__(16) __hip_bfloat16 Vt[16 * 520];
  __shared__ __align__(16) __hip_bfloat16 PQ[8][1536];

  const int tid = threadIdx.x;
  const int b = blockIdx.x & 63;        // XCD-aware: graph in low bits
  const int hh = blockIdx.x >> 6;
  const __hip_bfloat16* hrow = hbf + (size_t)b * 512 * 128;

  const int wave = tid >> 6;
  const int lane = tid & 63;
  const int l31 = lane & 31;
  const int l5 = lane >> 5;
  const int l15 = lane & 15;
  const int quad = lane >> 4;
  const int q0 = wave * 64;

  {
    f32x4 qacc[4], kacc[4], vacc[4];
#pragma unroll
    for (int mt = 0; mt < 4; ++mt) {
      qacc[mt] = (f32x4){0.f, 0.f, 0.f, 0.f};
      kacc[mt] = (f32x4){0.f, 0.f, 0.f, 0.f};
      vacc[mt] = (f32x4){0.f, 0.f, 0.f, 0.f};
    }
#pragma unroll
    for (int ks = 0; ks < 4; ++ks) {
      const int kc = ks * 32 + quad * 8;
      const bf16x8 wq = *(const bf16x8*)(qkvw_l + (size_t)(hh * 16 + l15) * 128 + kc);
      const bf16x8 wk = *(const bf16x8*)(qkvw_l + (size_t)(128 + hh * 16 + l15) * 128 + kc);
      const bf16x8 wv = *(const bf16x8*)(qkvw_l + (size_t)(256 + hh * 16 + l15) * 128 + kc);
#pragma unroll
      for (int mt = 0; mt < 4; ++mt) {
        const bf16x8 hf =
            *(const bf16x8*)(hrow + (size_t)(q0 + mt * 16 + l15) * 128 + kc);
        qacc[mt] = __builtin_amdgcn_mfma_f32_16x16x32_bf16(hf, wq, qacc[mt], 0, 0, 0);
        kacc[mt] = __builtin_amdgcn_mfma_f32_16x16x32_bf16(hf, wk, kacc[mt], 0, 0, 0);
        vacc[mt] = __builtin_amdgcn_mfma_f32_16x16x32_bf16(wv, hf, vacc[mt], 0, 0, 0);
      }
    }
    const float qb = qb_l[hh * 16 + l15];
    const float kb = qb_l[128 + hh * 16 + l15];
    const f32x4 vb = *(const f32x4*)(qb_l + 256 + hh * 16 + quad * 4);
#pragma unroll
    for (int mt = 0; mt < 4; ++mt)
#pragma unroll
      for (int r = 0; r < 4; ++r) {
        const int nd = mt * 16 + quad * 4 + r;
        PQ[wave][nd * 24 + l15] = bf_rta(qacc[mt][r] + qb);
        Ks[(q0 + nd) * 24 + l15] = bf_rta(kacc[mt][r] + kb);
        Vt[(quad * 4 + r) * 520 + q0 + mt * 16 + l15] = bf_rta(vacc[mt][r] + vb[r]);
      }
  }

  bf16x8 qf[2];
#pragma unroll
  for (int s = 0; s < 2; ++s)
    qf[s] = *(const bf16x8*)&PQ[wave][(s * 32 + l31) * 24 + l5 * 8];
  __syncthreads();

  __hip_bfloat16* Pw = &PQ[wave][0];
  const f32x16 z16 = {};
  f32x4 oacc[2][2];
#pragma unroll
  for (int s = 0; s < 2; ++s) { oacc[s][0] = (f32x4){0.f,0.f,0.f,0.f};
                                oacc[s][1] = (f32x4){0.f,0.f,0.f,0.f}; }
  float lacc[2] = {0.f, 0.f};

  // ---- pipeline prologue: kf and st for step (kt=0, s=0) ----
  bf16x8 kf = *(const bf16x8*)&Ks[(0 * 32 + l31) * 24 + l5 * 8];
  f32x16 st0 = __builtin_amdgcn_mfma_f32_32x32x16_bf16(kf, qf[0], z16, 0, 0, 0);

  for (int kt = 0; kt < 16; ++kt) {
    const bf16x8 vf = *(const bf16x8*)&Vt[l15 * 520 + kt * 32 + quad * 8];

    // ================= step (kt, s=0): uses st0 (computed a step ago) ====
    {
      float pr[16];
#pragma unroll
      for (int r = 0; r < 16; ++r) pr[r] = FAST_EXP2(st0[r]);
      const float a0 = (pr[0] + pr[1]) + (pr[2] + pr[3]);
      const float a1 = (pr[4] + pr[5]) + (pr[6] + pr[7]);
      const float a2 = (pr[8] + pr[9]) + (pr[10] + pr[11]);
      const float a3 = (pr[12] + pr[13]) + (pr[14] + pr[15]);
      lacc[0] += (a0 + a1) + (a2 + a3);
#pragma unroll
      for (int g = 0; g < 4; ++g) {
        *(uint2*)&Pw[l31 * 40 + g * 8 + l5 * 4] =
            make_uint2(pk_rta(pr[g * 4 + 0], pr[g * 4 + 1]),
                       pk_rta(pr[g * 4 + 2], pr[g * 4 + 3]));
      }
    }
    // next step's QK^T (s=1, same kf) — hides P write->read turnaround
    f32x16 st1 = __builtin_amdgcn_mfma_f32_32x32x16_bf16(kf, qf[1], z16, 0, 0, 0);
#pragma unroll
    for (int g = 0; g < 2; ++g) {
      const bf16x8 pf = *(const bf16x8*)&Pw[(g * 16 + l15) * 40 + quad * 8];
      oacc[0][g] = __builtin_amdgcn_mfma_f32_16x16x32_bf16(vf, pf, oacc[0][g], 0, 0, 0);
    }

    // ================= step (kt, s=1): uses st1 =========================
    {
      float pr[16];
#pragma unroll
      for (int r = 0; r < 16; ++r) pr[r] = FAST_EXP2(st1[r]);
      const float a0 = (pr[0] + pr[1]) + (pr[2] + pr[3]);
      const float a1 = (pr[4] + pr[5]) + (pr[6] + pr[7]);
      const float a2 = (pr[8] + pr[9]) + (pr[10] + pr[11]);
      const float a3 = (pr[12] + pr[13]) + (pr[14] + pr[15]);
      lacc[1] += (a0 + a1) + (a2 + a3);
#pragma unroll
      for (int g = 0; g < 4; ++g) {
        *(uint2*)&Pw[l31 * 40 + g * 8 + l5 * 4] =
            make_uint2(pk_rta(pr[g * 4 + 0], pr[g * 4 + 1]),
                       pk_rta(pr[g * 4 + 2], pr[g * 4 + 3]));
      }
    }
    // next kt's kf load + QK^T (s=0) — hides P write->read turnaround
    if (kt < 15) {
      kf = *(const bf16x8*)&Ks[((kt + 1) * 32 + l31) * 24 + l5 * 8];
      st0 = __builtin_amdgcn_mfma_f32_32x32x16_bf16(kf, qf[0], z16, 0, 0, 0);
    }
#pragma unroll
    for (int g = 0; g < 2; ++g) {
      const bf16x8 pf = *(const bf16x8*)&Pw[(g * 16 + l15) * 40 + quad * 8];
      oacc[1][g] = __builtin_amdgcn_mfma_f32_16x16x32_bf16(vf, pf, oacc[1][g], 0, 0, 0);
    }
  }

#pragma unroll
  for (int s = 0; s < 2; ++s) {
    const float lv = lacc[s] + __shfl_xor(lacc[s], 32, 64);
#pragma unroll
    for (int g = 0; g < 2; ++g) {
      const float lq = __shfl(lv, g * 16 + l15, 64);
      const float inv = 1.f / lq;
      const int qrow = q0 + s * 32 + g * 16 + l15;
      *(uint2*)(o + ((size_t)b * 512 + qrow) * 128 + hh * 16 + quad * 4) =
          make_uint2(pk_rta(oacc[s][g][0] * inv, oacc[s][g][1] * inv),
                     pk_rta(oacc[s][g][2] * inv, oacc[s][g][3] * inv));
    }
  }
}

// ---------------------------------------------------------------------------
// Mean-pool (bf16 h) + 128->64 relu -> 64->10 head. One block per graph.
// ---------------------------------------------------------------------------
__global__ __launch_bounds__(256) void head_kernel(
    const __hip_bfloat16* __restrict__ h,
    const float* __restrict__ w1, const float* __restrict__ b1,
    const float* __restrict__ w2, const float* __restrict__ b2,
    float* __restrict__ out)
{
  __shared__ float part[2][128];
  __shared__ float pooled[128];
  __shared__ float hid[64];

  const int b = blockIdx.x;
  const int tid = threadIdx.x;
  const int d = tid & 127;
  const int half = tid >> 7;

  const __hip_bfloat16* hp = h + ((size_t)b * 512 + (size_t)half * 256) * 128;
  float s = 0.f;
  for (int r = 0; r < 256; ++r) s += __bfloat162float(hp[(size_t)r * 128 + d]);
  part[half][d] = s;
  __syncthreads();

  if (tid < 128) pooled[tid] = (part[0][tid] + part[1][tid]) * (1.f / 512.f);
  __syncthreads();

  if (tid < 64) {
    float a = b1[tid];
    for (int dd = 0; dd < 128; ++dd) a = fmaf(pooled[dd], w1[dd * 64 + tid], a);
    hid[tid] = fmaxf(a, 0.f);
  }
  __syncthreads();

  if (tid < 10) {
    float a = b2[tid];
    for (int j = 0; j < 64; ++j) a = fmaf(hid[j], w2[j * 10 + tid], a);
    out[b * 10 + tid] = a;
  }
}

// ---------------------------------------------------------------------------
extern "C" void kernel_launch(void* const* d_in, const int* in_sizes, int n_in,
                              void* d_out, int out_size, void* d_ws, size_t ws_size,
                              hipStream_t stream)
{
  (void)in_sizes; (void)n_in; (void)out_size; (void)ws_size;

  const float* x      = (const float*)d_in[0];
  const float* Wp     = (const float*)d_in[4];
  const float* bp     = (const float*)d_in[5];
  const float* qkv_w  = (const float*)d_in[6];
  const float* qkv_b  = (const float*)d_in[7];
  const float* out_w  = (const float*)d_in[8];
  const float* out_b  = (const float*)d_in[9];
  const float* ln1_g  = (const float*)d_in[10];
  const float* ln1_b  = (const float*)d_in[11];
  const float* ffn_w1 = (const float*)d_in[12];
  const float* ffn_b1 = (const float*)d_in[13];
  const float* ffn_w2 = (const float*)d_in[14];
  const float* ffn_b2 = (const float*)d_in[15];
  const float* ln2_g  = (const float*)d_in[16];
  const float* ln2_b  = (const float*)d_in[17];
  const float* cw1    = (const float*)d_in[18];
  const float* cb1    = (const float*)d_in[19];
  const float* cw2    = (const float*)d_in[20];
  const float* cb2    = (const float*)d_in[21];

  const int N = NROWS;

  // ws (bf16 activations): hbf | xb | attnb | weights | qb_s
  __hip_bfloat16* hbf   = (__hip_bfloat16*)d_ws;
  __hip_bfloat16* xb    = hbf + (size_t)N * 128;
  __hip_bfloat16* attnb = xb + (size_t)N * 128;
  __hip_bfloat16* wp_t  = attnb + (size_t)N * 128;
  __hip_bfloat16* qkvw  = wp_t + 128 * 128;
  __hip_bfloat16* outw  = qkvw + 6 * 384 * 128;
  __hip_bfloat16* w1t   = outw + 6 * 128 * 128;
  __hip_bfloat16* w2t   = w1t + 6 * 512 * 128;
  float* qb_s = (float*)(w2t + 6 * 128 * 512);

  const dim3 blk(256);
  __hip_bfloat16* const nob = (__hip_bfloat16*)nullptr;
  const float* const nof = (const float*)nullptr;

  // ---- single merged prep dispatch ----
  prep_kernel<<<dim3((PB7 + 255) / 256), blk, 0, stream>>>(
      x, xb, Wp, wp_t, qkv_w, qkvw, qkv_b, qb_s, out_w, outw,
      ffn_w1, w1t, ffn_w2, w2t);

  // ---- input projection: hbf = bf16(x @ Wp + bp) ----
  gemm_fk<<<dim3(N / 64), blk, 0, stream>>>(
      xb, wp_t, bp, hbf, nob, nof, nof, N, 128, 0);

  for (int i = 0; i < NLAYER; ++i) {
    // fused QKV + attention (XCD-swizzled grid)
    attn_kernel<<<dim3(64 * 8), dim3(512), 0, stream>>>(
        hbf, qkvw + (size_t)i * 384 * 128, qb_s + (size_t)i * 384, attnb);

    // hbf = LN2( h1 + relu(h1@W1+b1)@W2 + b2 ), h1 = LN1(hbf + attnb@ow^T + ob)
    oproj_ffn<<<dim3(N / 64), blk, 0, stream>>>(
        attnb, hbf,
        outw + (size_t)i * 128 * 128, out_b + (size_t)i * 128,
        ln1_g + (size_t)i * 128, ln1_b + (size_t)i * 128,
        w1t + (size_t)i * 512 * 128, w2t + (size_t)i * 128 * 512,
        ffn_b1 + (size_t)i * 512, ffn_b2 + (size_t)i * 128,
        ln2_g + (size_t)i * 128, ln2_b + (size_t)i * 128);
  }

  head_kernel<<<dim3(64), blk, 0, stream>>>(hbf, cw1, cb1, cw2, cb2, (float*)d_out);
}

// Round 15
// 476.766 us; speedup vs baseline: 1.0575x; 1.0138x over previous
//
#include <hip/hip_runtime.h>
#include <hip/hip_bf16.h>

// Dense transformer forward, round 29: input-path trim on the locked-in R19
// structure (483.4us measured). The xb round-trip is removed: gemm_in stages
// f32 x directly with in-staging __float2bfloat16 conversion (bit-identical
// h0 vs prep's f2bf + bf16 reload), deleting 16.8MB HBM reads + 8.4MB
// writes and shrinking prep's grid 19.3K -> 4.7K blocks (x-conversion was
// 78% of its threads; prep is serial-before-everything). attn / oproj_ffn /
// head are byte-identical to R28 (the session best). Numerics identical.
// B=64 x L=512, D=128, H=8 (DH=16), LAYERS=6, FF=512, OUT=10.

#define NROWS (64 * 512)
#define NLAYER 6

typedef __bf16 bf16x8 __attribute__((ext_vector_type(8)));
typedef float  f32x4  __attribute__((ext_vector_type(4)));
typedef float  f32x16 __attribute__((ext_vector_type(16)));

#define QSCALE 0.36067376022224085f   // 1/sqrt(16) * log2(e)

#if defined(__has_builtin)
#  if __has_builtin(__builtin_amdgcn_exp2f)
#    define FAST_EXP2(x) __builtin_amdgcn_exp2f(x)
#  endif
#endif
#ifndef FAST_EXP2
#  define FAST_EXP2(x) __expf((x) * 0.6931471805599453f)
#endif

__device__ __forceinline__ __hip_bfloat16 f2bf(float x) { return __float2bfloat16(x); }

__device__ __forceinline__ __hip_bfloat16 bf_rta(float a) {
  union { float f; unsigned u; } c{a};
  return __builtin_bit_cast(__hip_bfloat16, (unsigned short)((c.u + 0x8000u) >> 16));
}
__device__ __forceinline__ unsigned pk_rta(float a, float b) {
  union { float f; unsigned u; } ca{a}, cb{b};
  return ((ca.u + 0x8000u) >> 16) | ((cb.u + 0x8000u) & 0xFFFF0000u);
}
// pack two floats with the SAME rounding prep used (__float2bfloat16/RTNE)
__device__ __forceinline__ unsigned pk_bf(float a, float b) {
  const unsigned short ua =
      __builtin_bit_cast(unsigned short, __float2bfloat16(a));
  const unsigned short ub =
      __builtin_bit_cast(unsigned short, __float2bfloat16(b));
  return (unsigned)ua | ((unsigned)ub << 16);
}
__device__ __forceinline__ float bf_hi(unsigned u) {          // element 1 of pair
  return __builtin_bit_cast(float, u & 0xFFFF0000u);
}
__device__ __forceinline__ float bf_lo(unsigned u) {          // element 0 of pair
  return __builtin_bit_cast(float, u << 16);
}

// ---------------------------------------------------------------------------
// Merged prep (weights only now): conversions/transposes + scaled qkv bias.
// ---------------------------------------------------------------------------
#define PN_WP  (128 * 128)
#define PN_QW  (6 * 384 * 128)
#define PN_QB  (6 * 384)
#define PN_OW  (6 * 128 * 128)
#define PN_W1  (6 * 128 * 512)
#define PN_W2  (6 * 512 * 128)
#define QB1 PN_WP
#define QB2 (QB1 + PN_QW)
#define QB3 (QB2 + PN_QB)
#define QB4 (QB3 + PN_OW)
#define QB5 (QB4 + PN_W1)
#define QB6 (QB5 + PN_W2)

__global__ __launch_bounds__(256) void prep_kernel(
    const float* __restrict__ Wp, __hip_bfloat16* __restrict__ wp_t,
    const float* __restrict__ qkv_w, __hip_bfloat16* __restrict__ qkvw,
    const float* __restrict__ qkv_b, float* __restrict__ qb_s,
    const float* __restrict__ out_w, __hip_bfloat16* __restrict__ outw,
    const float* __restrict__ ffn_w1, __hip_bfloat16* __restrict__ w1t,
    const float* __restrict__ ffn_w2, __hip_bfloat16* __restrict__ w2t)
{
  const int idx = blockIdx.x * 256 + threadIdx.x;
  if (idx < QB1) {
    const int i = idx;
    const int c = i >> 7, r = i & 127;
    wp_t[i] = f2bf(Wp[r * 128 + c]);
  } else if (idx < QB2) {
    const int i = idx - QB1;
    const int row = (i >> 7) % 384;
    qkvw[i] = f2bf(qkv_w[i] * ((row < 128) ? QSCALE : 1.f));
  } else if (idx < QB3) {
    const int i = idx - QB2;
    qb_s[i] = qkv_b[i] * (((i % 384) < 128) ? QSCALE : 1.f);
  } else if (idx < QB4) {
    const int i = idx - QB3;
    outw[i] = f2bf(out_w[i]);
  } else if (idx < QB5) {
    const int i = idx - QB4;                 // [l][c][r], R=128, C=512
    const int l = i >> 16, j = i & 65535;
    const int c = j >> 7, r = j & 127;
    w1t[i] = f2bf(ffn_w1[l * 65536 + r * 512 + c]);
  } else if (idx < QB6) {
    const int i = idx - QB5;                 // [l][c][r], R=512, C=128
    const int l = i >> 16, j = i & 65535;
    const int c = j >> 9, r = j & 511;
    w2t[i] = f2bf(ffn_w2[l * 65536 + r * 128 + c]);
  }
}

// ---------------------------------------------------------------------------
// gemm_in: input projection with f32 A staged directly (in-staging f2bf
// conversion — bit-identical to the old prep->xb->gemm_fk path). K=128,
// Nn=128, 64 rows/block, same tile/MFMA structure as the retired gemm_fk.
//   hbf = bf16(x @ wp_t^T + bp)
// ---------------------------------------------------------------------------
__global__ __launch_bounds__(256) void gemm_in(
    const float* __restrict__ A,             // [M][128] f32
    const __hip_bfloat16* __restrict__ B,    // [128 n][128 k] bf16
    const float* __restrict__ bias,
    __hip_bfloat16* __restrict__ outb)
{
  __shared__ __align__(16) __hip_bfloat16 As[64 * 136];
  __shared__ __align__(16) __hip_bfloat16 Bs[128 * 136];

  const int tid = threadIdx.x;
  const int m0 = blockIdx.x << 6;
  const int wave = tid >> 6;
  const int lane = tid & 63;
  const int quad = lane >> 4;
  const int l15 = lane & 15;
  const int wrow = wave * 16;

  f32x4 acc[8];
#pragma unroll
  for (int ni = 0; ni < 8; ++ni) acc[ni] = (f32x4){0.f, 0.f, 0.f, 0.f};

  // ---- stage A (64x128 f32 -> bf16) and B (128x128 bf16) ----
#pragma unroll
  for (int p = 0; p < 4; ++p) {
    const int e = tid + (p << 8);
    const int row = e >> 4;
    const int c = e & 15;
    const float4 fa = *(const float4*)(A + (size_t)(m0 + row) * 128 + c * 8);
    const float4 fb = *(const float4*)(A + (size_t)(m0 + row) * 128 + c * 8 + 4);
    uint4 u;
    u.x = pk_bf(fa.x, fa.y);
    u.y = pk_bf(fa.z, fa.w);
    u.z = pk_bf(fb.x, fb.y);
    u.w = pk_bf(fb.z, fb.w);
    *(uint4*)&As[row * 136 + c * 8] = u;
  }
#pragma unroll
  for (int p = 0; p < 8; ++p) {
    const int e = tid + (p << 8);
    const int row = e >> 4;
    const int c = e & 15;
    *(uint4*)&Bs[row * 136 + c * 8] =
        *(const uint4*)(B + (size_t)row * 128 + c * 8);
  }
  __syncthreads();

#pragma unroll
  for (int ks = 0; ks < 4; ++ks) {
    const bf16x8 af = *(const bf16x8*)&As[(wrow + l15) * 136 + ks * 32 + quad * 8];
#pragma unroll
    for (int ni = 0; ni < 8; ++ni) {
      const bf16x8 bfr =
          *(const bf16x8*)&Bs[(ni * 16 + l15) * 136 + ks * 32 + quad * 8];
      acc[ni] = __builtin_amdgcn_mfma_f32_16x16x32_bf16(af, bfr, acc[ni], 0, 0, 0);
    }
  }

#pragma unroll
  for (int ni = 0; ni < 8; ++ni) {
    const int cl = ni * 16 + l15;
    const float bv = bias[cl];
#pragma unroll
    for (int r = 0; r < 4; ++r) {
      outb[(size_t)(m0 + wrow + quad * 4 + r) * 128 + cl] =
          bf_rta(acc[ni][r] + bv);
    }
  }
}

// ---------------------------------------------------------------------------
// Fused outproj + residual + LN1 + FFN + residual + LN2 (R16 version).
// ---------------------------------------------------------------------------
__global__ __launch_bounds__(256) void oproj_ffn(
    const __hip_bfloat16* __restrict__ ab,   // attn output (A of outproj)
    __hip_bfloat16* __restrict__ hb,         // residual in, final out
    const __hip_bfloat16* __restrict__ ow,   // layer [128 n][128 k] bf16
    const float* __restrict__ ob,
    const float* __restrict__ ln1g, const float* __restrict__ ln1b,
    const __hip_bfloat16* __restrict__ w1,   // layer [512 n][128 k] bf16
    const __hip_bfloat16* __restrict__ w2,   // layer [128 n][512 k] bf16
    const float* __restrict__ fb1, const float* __restrict__ fb2,
    const float* __restrict__ ln2g, const float* __restrict__ ln2b)
{
  __shared__ __align__(16) __hip_bfloat16 AF[64 * 136];   // A / h1 / F
  __shared__ __align__(16) __hip_bfloat16 Bs[128 * 136];  // ow / W1c / W2c

  const int tid = threadIdx.x;
  const int m0 = blockIdx.x << 6;
  const int wave = tid >> 6;
  const int lane = tid & 63;
  const int quad = lane >> 4;
  const int l15 = lane & 15;
  const int wrow = wave * 16;
  const int node = m0 + wrow + l15;        // this lane's node (transposed lyt)
  const int ch0 = quad * 4;                // channel base within each ni group

  // ---- early residual load: 8x uint2; latency hides under staging+GEMM ----
  uint2 hres[8];
#pragma unroll
  for (int ni = 0; ni < 8; ++ni)
    hres[ni] = *(const uint2*)(hb + (size_t)node * 128 + ni * 16 + ch0);

  // ---- stage attnb tile (64x128) and ow (128x128) ----
#pragma unroll
  for (int p = 0; p < 4; ++p) {
    const int e = tid + (p << 8);
    const int row = e >> 4, c = e & 15;
    *(uint4*)&AF[row * 136 + c * 8] =
        *(const uint4*)(ab + (size_t)(m0 + row) * 128 + c * 8);
  }
#pragma unroll
  for (int p = 0; p < 8; ++p) {
    const int e = tid + (p << 8);
    const int row = e >> 4, c = e & 15;
    *(uint4*)&Bs[row * 136 + c * 8] =
        *(const uint4*)(ow + (size_t)row * 128 + c * 8);
  }
  __syncthreads();

  // attnb frags (node rows; usable as B-operand = A^T)
  bf16x8 af[4];
#pragma unroll
  for (int ks = 0; ks < 4; ++ks)
    af[ks] = *(const bf16x8*)&AF[(wrow + l15) * 136 + ks * 32 + quad * 8];

  // ---- outproj, transposed: acc[ni][r] = O[ch = ni*16+ch0+r][node] ----
  f32x4 acc[8];
#pragma unroll
  for (int ni = 0; ni < 8; ++ni) acc[ni] = (f32x4){0.f, 0.f, 0.f, 0.f};
#pragma unroll
  for (int ks = 0; ks < 4; ++ks)
#pragma unroll
    for (int ni = 0; ni < 8; ++ni) {
      const bf16x8 bfr =
          *(const bf16x8*)&Bs[(ni * 16 + l15) * 136 + ks * 32 + quad * 8];
      acc[ni] = __builtin_amdgcn_mfma_f32_16x16x32_bf16(bfr, af[ks], acc[ni], 0, 0, 0);
    }

  // ---- residual + LN1 (cross-quad reduce); h1 -> AF wave-private rows ----
  {
    float s = 0.f, sq = 0.f;
#pragma unroll
    for (int ni = 0; ni < 8; ++ni) {
      const f32x4 obv = *(const f32x4*)(ob + ni * 16 + ch0);
#pragma unroll
      for (int r = 0; r < 4; ++r) {
        const unsigned hu = (r & 2) ? hres[ni].y : hres[ni].x;
        const float hv = (r & 1) ? bf_hi(hu) : bf_lo(hu);
        const float v = acc[ni][r] + obv[r] + hv;
        acc[ni][r] = v;
        s += v;
        sq += v * v;
      }
    }
    s += __shfl_xor(s, 16, 64);  sq += __shfl_xor(sq, 16, 64);
    s += __shfl_xor(s, 32, 64);  sq += __shfl_xor(sq, 32, 64);
    const float mean = s * (1.f / 128.f);
    const float rs = rsqrtf(sq * (1.f / 128.f) - mean * mean + 1e-5f);
#pragma unroll
    for (int ni = 0; ni < 8; ++ni) {
      const f32x4 gv = *(const f32x4*)(ln1g + ni * 16 + ch0);
      const f32x4 bv = *(const f32x4*)(ln1b + ni * 16 + ch0);
      const float o0 = (acc[ni][0] - mean) * rs * gv[0] + bv[0];
      const float o1 = (acc[ni][1] - mean) * rs * gv[1] + bv[1];
      const float o2 = (acc[ni][2] - mean) * rs * gv[2] + bv[2];
      const float o3 = (acc[ni][3] - mean) * rs * gv[3] + bv[3];
      const uint2 pk = make_uint2(pk_rta(o0, o1), pk_rta(o2, o3));
      hres[ni] = pk;   // bf16 h1 for the LN2 residual (bit-exact vs AF copy)
      *(uint2*)&AF[(wrow + l15) * 136 + ni * 16 + ch0] = pk;
    }
  }

  // ---- FFN ----
  __syncthreads();   // all waves done reading ow from Bs
#pragma unroll
  for (int p = 0; p < 8; ++p) {     // stage W1 chunk 0
    const int e = tid + (p << 8);
    const int row = e >> 4, cc = e & 15;
    *(uint4*)&Bs[row * 136 + cc * 8] =
        *(const uint4*)(w1 + (size_t)row * 128 + cc * 8);
  }
  // h1 frags from AF (in-wave ordering vs this wave's LN writes)
  bf16x8 hf[4];
#pragma unroll
  for (int ks = 0; ks < 4; ++ks)
    hf[ks] = *(const bf16x8*)&AF[(wrow + l15) * 136 + ks * 32 + quad * 8];
  __syncthreads();   // W1c0 staged

  f32x4 facc[8];
#pragma unroll
  for (int ni = 0; ni < 8; ++ni) facc[ni] = (f32x4){0.f, 0.f, 0.f, 0.f};

  for (int c = 0; c < 4; ++c) {
    if (c > 0) {
      __syncthreads();   // W2 reads of previous chunk complete
#pragma unroll
      for (int p = 0; p < 8; ++p) {
        const int e = tid + (p << 8);
        const int row = e >> 4, cc = e & 15;
        *(uint4*)&Bs[row * 136 + cc * 8] =
            *(const uint4*)(w1 + (size_t)(c * 128 + row) * 128 + cc * 8);
      }
      __syncthreads();
    }

    // ---- F chunk, transposed: fc[ni] = F[n1 = ni*16+ch0+r][node] ----
    f32x4 fc[8];
#pragma unroll
    for (int ni = 0; ni < 8; ++ni) fc[ni] = (f32x4){0.f, 0.f, 0.f, 0.f};
#pragma unroll
    for (int ks = 0; ks < 4; ++ks)
#pragma unroll
      for (int ni = 0; ni < 8; ++ni) {
        const bf16x8 wf =
            *(const bf16x8*)&Bs[(ni * 16 + l15) * 136 + ks * 32 + quad * 8];
        fc[ni] = __builtin_amdgcn_mfma_f32_16x16x32_bf16(wf, hf[ks], fc[ni], 0, 0, 0);
      }
    // bias + relu + pack into AF[node row][n1 = ni*16 + ch0 + r]
#pragma unroll
    for (int ni = 0; ni < 8; ++ni) {
      const f32x4 bv = *(const f32x4*)(fb1 + c * 128 + ni * 16 + ch0);
      const float v0 = fmaxf(fc[ni][0] + bv[0], 0.f);
      const float v1 = fmaxf(fc[ni][1] + bv[1], 0.f);
      const float v2 = fmaxf(fc[ni][2] + bv[2], 0.f);
      const float v3 = fmaxf(fc[ni][3] + bv[3], 0.f);
      *(uint2*)&AF[(wrow + l15) * 136 + ni * 16 + ch0] =
          make_uint2(pk_rta(v0, v1), pk_rta(v2, v3));
    }
    __syncthreads();   // all waves done reading W1c from Bs

    // ---- stage W2 chunk c (k = c*128 .. +128 of [128][512]) ----
#pragma unroll
    for (int p = 0; p < 8; ++p) {
      const int e = tid + (p << 8);
      const int row = e >> 4, cc = e & 15;
      *(uint4*)&Bs[row * 136 + cc * 8] =
          *(const uint4*)(w2 + (size_t)row * 512 + c * 128 + cc * 8);
    }
    __syncthreads();

    // ---- out += W2_c @ F_c, transposed: facc[ni][r] = out[ch][node] ----
#pragma unroll
    for (int ks2 = 0; ks2 < 4; ++ks2) {
      const bf16x8 ff =
          *(const bf16x8*)&AF[(wrow + l15) * 136 + ks2 * 32 + quad * 8];
#pragma unroll
      for (int ni = 0; ni < 8; ++ni) {
        const bf16x8 wf =
            *(const bf16x8*)&Bs[(ni * 16 + l15) * 136 + ks2 * 32 + quad * 8];
        facc[ni] = __builtin_amdgcn_mfma_f32_16x16x32_bf16(wf, ff, facc[ni], 0, 0, 0);
      }
    }
  }

  // ---- final residual (hres regs) + LN2 -> hb, vectorized stores ----
  {
    float s = 0.f, sq = 0.f;
#pragma unroll
    for (int ni = 0; ni < 8; ++ni) {
      const f32x4 b2v = *(const f32x4*)(fb2 + ni * 16 + ch0);
#pragma unroll
      for (int r = 0; r < 4; ++r) {
        const unsigned hu = (r & 2) ? hres[ni].y : hres[ni].x;
        const float hv = (r & 1) ? bf_hi(hu) : bf_lo(hu);
        const float v = facc[ni][r] + b2v[r] + hv;
        facc[ni][r] = v;
        s += v;
        sq += v * v;
      }
    }
    s += __shfl_xor(s, 16, 64);  sq += __shfl_xor(sq, 16, 64);
    s += __shfl_xor(s, 32, 64);  sq += __shfl_xor(sq, 32, 64);
    const float mean = s * (1.f / 128.f);
    const float rs = rsqrtf(sq * (1.f / 128.f) - mean * mean + 1e-5f);
#pragma unroll
    for (int ni = 0; ni < 8; ++ni) {
      const f32x4 gv = *(const f32x4*)(ln2g + ni * 16 + ch0);
      const f32x4 bv = *(const f32x4*)(ln2b + ni * 16 + ch0);
      const float o0 = (facc[ni][0] - mean) * rs * gv[0] + bv[0];
      const float o1 = (facc[ni][1] - mean) * rs * gv[1] + bv[1];
      const float o2 = (facc[ni][2] - mean) * rs * gv[2] + bv[2];
      const float o3 = (facc[ni][3] - mean) * rs * gv[3] + bv[3];
      *(uint2*)(hb + (size_t)node * 128 + ni * 16 + ch0) =
          make_uint2(pk_rta(o0, o1), pk_rta(o2, o3));
    }
  }
}

// ---------------------------------------------------------------------------
// Fused QKV + flash attention (R19, byte-identical): P stride 40, single
// buffer, PQ[8][1536], two-stage (kt,s) st prefetch.
// ---------------------------------------------------------------------------
__global__ __launch_bounds__(512) void attn_kernel(
    const __hip_bfloat16* __restrict__ hbf,
    const __hip_bfloat16* __restrict__ qkvw_l,
    const float* __restrict__ qb_l,
    __hip_bfloat16* __restrict__ o)
{
  __shared__ __align__(16) __hip_bfloat16 Ks[512 * 24];
  __shared__ __align__(16) __hip_bfloat16 Vt[16 * 520];
  __shared__ __align__(16) __hip_bfloat16 PQ[8][1536];

  const int tid = threadIdx.x;
  const int b = blockIdx.x & 63;        // XCD-aware: graph in low bits
  const int hh = blockIdx.x >> 6;
  const __hip_bfloat16* hrow = hbf + (size_t)b * 512 * 128;

  const int wave = tid >> 6;
  const int lane = tid & 63;
  const int l31 = lane & 31;
  const int l5 = lane >> 5;
  const int l15 = lane & 15;
  const int quad = lane >> 4;
  const int q0 = wave * 64;

  {
    f32x4 qacc[4], kacc[4], vacc[4];
#pragma unroll
    for (int mt = 0; mt < 4; ++mt) {
      qacc[mt] = (f32x4){0.f, 0.f, 0.f, 0.f};
      kacc[mt] = (f32x4){0.f, 0.f, 0.f, 0.f};
      vacc[mt] = (f32x4){0.f, 0.f, 0.f, 0.f};
    }
#pragma unroll
    for (int ks = 0; ks < 4; ++ks) {
      const int kc = ks * 32 + quad * 8;
      const bf16x8 wq = *(const bf16x8*)(qkvw_l + (size_t)(hh * 16 + l15) * 128 + kc);
      const bf16x8 wk = *(const bf16x8*)(qkvw_l + (size_t)(128 + hh * 16 + l15) * 128 + kc);
      const bf16x8 wv = *(const bf16x8*)(qkvw_l + (size_t)(256 + hh * 16 + l15) * 128 + kc);
#pragma unroll
      for (int mt = 0; mt < 4; ++mt) {
        const bf16x8 hf =
            *(const bf16x8*)(hrow + (size_t)(q0 + mt * 16 + l15) * 128 + kc);
        qacc[mt] = __builtin_amdgcn_mfma_f32_16x16x32_bf16(hf, wq, qacc[mt], 0, 0, 0);
        kacc[mt] = __builtin_amdgcn_mfma_f32_16x16x32_bf16(hf, wk, kacc[mt], 0, 0, 0);
        vacc[mt] = __builtin_amdgcn_mfma_f32_16x16x32_bf16(wv, hf, vacc[mt], 0, 0, 0);
      }
    }
    const float qb = qb_l[hh * 16 + l15];
    const float kb = qb_l[128 + hh * 16 + l15];
    const f32x4 vb = *(const f32x4*)(qb_l + 256 + hh * 16 + quad * 4);
#pragma unroll
    for (int mt = 0; mt < 4; ++mt)
#pragma unroll
      for (int r = 0; r < 4; ++r) {
        const int nd = mt * 16 + quad * 4 + r;
        PQ[wave][nd * 24 + l15] = bf_rta(qacc[mt][r] + qb);
        Ks[(q0 + nd) * 24 + l15] = bf_rta(kacc[mt][r] + kb);
        Vt[(quad * 4 + r) * 520 + q0 + mt * 16 + l15] = bf_rta(vacc[mt][r] + vb[r]);
      }
  }

  bf16x8 qf[2];
#pragma unroll
  for (int s = 0; s < 2; ++s)
    qf[s] = *(const bf16x8*)&PQ[wave][(s * 32 + l31) * 24 + l5 * 8];
  __syncthreads();

  __hip_bfloat16* Pw = &PQ[wave][0];
  const f32x16 z16 = {};
  f32x4 oacc[2][2];
#pragma unroll
  for (int s = 0; s < 2; ++s) { oacc[s][0] = (f32x4){0.f,0.f,0.f,0.f};
                                oacc[s][1] = (f32x4){0.f,0.f,0.f,0.f}; }
  float lacc[2] = {0.f, 0.f};

  // ---- pipeline prologue: kf and st for step (kt=0, s=0) ----
  bf16x8 kf = *(const bf16x8*)&Ks[(0 * 32 + l31) * 24 + l5 * 8];
  f32x16 st0 = __builtin_amdgcn_mfma_f32_32x32x16_bf16(kf, qf[0], z16, 0, 0, 0);

  for (int kt = 0; kt < 16; ++kt) {
    const bf16x8 vf = *(const bf16x8*)&Vt[l15 * 520 + kt * 32 + quad * 8];

    // ================= step (kt, s=0): uses st0 (computed a step ago) ====
    {
      float pr[16];
#pragma unroll
      for (int r = 0; r < 16; ++r) pr[r] = FAST_EXP2(st0[r]);
      const float a0 = (pr[0] + pr[1]) + (pr[2] + pr[3]);
      const float a1 = (pr[4] + pr[5]) + (pr[6] + pr[7]);
      const float a2 = (pr[8] + pr[9]) + (pr[10] + pr[11]);
      const float a3 = (pr[12] + pr[13]) + (pr[14] + pr[15]);
      lacc[0] += (a0 + a1) + (a2 + a3);
#pragma unroll
      for (int g = 0; g < 4; ++g) {
        *(uint2*)&Pw[l31 * 40 + g * 8 + l5 * 4] =
            make_uint2(pk_rta(pr[g * 4 + 0], pr[g * 4 + 1]),
                       pk_rta(pr[g * 4 + 2], pr[g * 4 + 3]));
      }
    }
    // next step's QK^T (s=1, same kf) — hides P write->read turnaround
    f32x16 st1 = __builtin_amdgcn_mfma_f32_32x32x16_bf16(kf, qf[1], z16, 0, 0, 0);
#pragma unroll
    for (int g = 0; g < 2; ++g) {
      const bf16x8 pf = *(const bf16x8*)&Pw[(g * 16 + l15) * 40 + quad * 8];
      oacc[0][g] = __builtin_amdgcn_mfma_f32_16x16x32_bf16(vf, pf, oacc[0][g], 0, 0, 0);
    }

    // ================= step (kt, s=1): uses st1 =========================
    {
      float pr[16];
#pragma unroll
      for (int r = 0; r < 16; ++r) pr[r] = FAST_EXP2(st1[r]);
      const float a0 = (pr[0] + pr[1]) + (pr[2] + pr[3]);
      const float a1 = (pr[4] + pr[5]) + (pr[6] + pr[7]);
      const float a2 = (pr[8] + pr[9]) + (pr[10] + pr[11]);
      const float a3 = (pr[12] + pr[13]) + (pr[14] + pr[15]);
      lacc[1] += (a0 + a1) + (a2 + a3);
#pragma unroll
      for (int g = 0; g < 4; ++g) {
        *(uint2*)&Pw[l31 * 40 + g * 8 + l5 * 4] =
            make_uint2(pk_rta(pr[g * 4 + 0], pr[g * 4 + 1]),
                       pk_rta(pr[g * 4 + 2], pr[g * 4 + 3]));
      }
    }
    // next kt's kf load + QK^T (s=0) — hides P write->read turnaround
    if (kt < 15) {
      kf = *(const bf16x8*)&Ks[((kt + 1) * 32 + l31) * 24 + l5 * 8];
      st0 = __builtin_amdgcn_mfma_f32_32x32x16_bf16(kf, qf[0], z16, 0, 0, 0);
    }
#pragma unroll
    for (int g = 0; g < 2; ++g) {
      const bf16x8 pf = *(const bf16x8*)&Pw[(g * 16 + l15) * 40 + quad * 8];
      oacc[1][g] = __builtin_amdgcn_mfma_f32_16x16x32_bf16(vf, pf, oacc[1][g], 0, 0, 0);
    }
  }

#pragma unroll
  for (int s = 0; s < 2; ++s) {
    const float lv = lacc[s] + __shfl_xor(lacc[s], 32, 64);
#pragma unroll
    for (int g = 0; g < 2; ++g) {
      const float lq = __shfl(lv, g * 16 + l15, 64);
      const float inv = 1.f / lq;
      const int qrow = q0 + s * 32 + g * 16 + l15;
      *(uint2*)(o + ((size_t)b * 512 + qrow) * 128 + hh * 16 + quad * 4) =
          make_uint2(pk_rta(oacc[s][g][0] * inv, oacc[s][g][1] * inv),
                     pk_rta(oacc[s][g][2] * inv, oacc[s][g][3] * inv));
    }
  }
}

// ---------------------------------------------------------------------------
// Mean-pool (bf16 h) + 128->64 relu -> 64->10 head. One block per graph.
// ---------------------------------------------------------------------------
__global__ __launch_bounds__(256) void head_kernel(
    const __hip_bfloat16* __restrict__ h,
    const float* __restrict__ w1, const float* __restrict__ b1,
    const float* __restrict__ w2, const float* __restrict__ b2,
    float* __restrict__ out)
{
  __shared__ float part[2][128];
  __shared__ float pooled[128];
  __shared__ float hid[64];

  const int b = blockIdx.x;
  const int tid = threadIdx.x;
  const int d = tid & 127;
  const int half = tid >> 7;

  const __hip_bfloat16* hp = h + ((size_t)b * 512 + (size_t)half * 256) * 128;
  float s = 0.f;
  for (int r = 0; r < 256; ++r) s += __bfloat162float(hp[(size_t)r * 128 + d]);
  part[half][d] = s;
  __syncthreads();

  if (tid < 128) pooled[tid] = (part[0][tid] + part[1][tid]) * (1.f / 512.f);
  __syncthreads();

  if (tid < 64) {
    float a = b1[tid];
    for (int dd = 0; dd < 128; ++dd) a = fmaf(pooled[dd], w1[dd * 64 + tid], a);
    hid[tid] = fmaxf(a, 0.f);
  }
  __syncthreads();

  if (tid < 10) {
    float a = b2[tid];
    for (int j = 0; j < 64; ++j) a = fmaf(hid[j], w2[j * 10 + tid], a);
    out[b * 10 + tid] = a;
  }
}

// ---------------------------------------------------------------------------
extern "C" void kernel_launch(void* const* d_in, const int* in_sizes, int n_in,
                              void* d_out, int out_size, void* d_ws, size_t ws_size,
                              hipStream_t stream)
{
  (void)in_sizes; (void)n_in; (void)out_size; (void)ws_size;

  const float* x      = (const float*)d_in[0];
  const float* Wp     = (const float*)d_in[4];
  const float* bp     = (const float*)d_in[5];
  const float* qkv_w  = (const float*)d_in[6];
  const float* qkv_b  = (const float*)d_in[7];
  const float* out_w  = (const float*)d_in[8];
  const float* out_b  = (const float*)d_in[9];
  const float* ln1_g  = (const float*)d_in[10];
  const float* ln1_b  = (const float*)d_in[11];
  const float* ffn_w1 = (const float*)d_in[12];
  const float* ffn_b1 = (const float*)d_in[13];
  const float* ffn_w2 = (const float*)d_in[14];
  const float* ffn_b2 = (const float*)d_in[15];
  const float* ln2_g  = (const float*)d_in[16];
  const float* ln2_b  = (const float*)d_in[17];
  const float* cw1    = (const float*)d_in[18];
  const float* cb1    = (const float*)d_in[19];
  const float* cw2    = (const float*)d_in[20];
  const float* cb2    = (const float*)d_in[21];

  const int N = NROWS;

  // ws (bf16 activations): hbf | (xb slot, unused) | attnb | weights | qb_s
  __hip_bfloat16* hbf   = (__hip_bfloat16*)d_ws;
  __hip_bfloat16* xb    = hbf + (size_t)N * 128;     // retained slot (unused)
  __hip_bfloat16* attnb = xb + (size_t)N * 128;
  __hip_bfloat16* wp_t  = attnb + (size_t)N * 128;
  __hip_bfloat16* qkvw  = wp_t + 128 * 128;
  __hip_bfloat16* outw  = qkvw + 6 * 384 * 128;
  __hip_bfloat16* w1t   = outw + 6 * 128 * 128;
  __hip_bfloat16* w2t   = w1t + 6 * 512 * 128;
  float* qb_s = (float*)(w2t + 6 * 128 * 512);

  const dim3 blk(256);

  // ---- merged weight-prep dispatch (x conversion now fused into gemm_in) ----
  prep_kernel<<<dim3((QB6 + 255) / 256), blk, 0, stream>>>(
      Wp, wp_t, qkv_w, qkvw, qkv_b, qb_s, out_w, outw,
      ffn_w1, w1t, ffn_w2, w2t);

  // ---- input projection: hbf = bf16(x @ Wp + bp), f32 A staged directly ----
  gemm_in<<<dim3(N / 64), blk, 0, stream>>>(x, wp_t, bp, hbf);

  for (int i = 0; i < NLAYER; ++i) {
    // fused QKV + attention (XCD-swizzled grid)
    attn_kernel<<<dim3(64 * 8), dim3(512), 0, stream>>>(
        hbf, qkvw + (size_t)i * 384 * 128, qb_s + (size_t)i * 384, attnb);

    // hbf = LN2( h1 + relu(h1@W1+b1)@W2 + b2 ), h1 = LN1(hbf + attnb@ow^T + ob)
    oproj_ffn<<<dim3(N / 64), blk, 0, stream>>>(
        attnb, hbf,
        outw + (size_t)i * 128 * 128, out_b + (size_t)i * 128,
        ln1_g + (size_t)i * 128, ln1_b + (size_t)i * 128,
        w1t + (size_t)i * 512 * 128, w2t + (size_t)i * 128 * 512,
        ffn_b1 + (size_t)i * 512, ffn_b2 + (size_t)i * 128,
        ln2_g + (size_t)i * 128, ln2_b + (size_t)i * 128);
  }

  head_kernel<<<dim3(64), blk, 0, stream>>>(hbf, cw1, cb1, cw2, cb2, (float*)d_out);
}